// Round 9
// baseline (309.454 us; speedup 1.0000x reference)
//
#include <hip/hip_runtime.h>
#include <math.h>

#define BB 8
#define TT 1024
#define CC 768
#define NH 12
#define HD 64
#define LOG2E 1.44269504088896f

typedef __attribute__((ext_vector_type(8))) _Float16 hv8;   // 8 fp16 (4 VGPRs)
typedef __attribute__((ext_vector_type(8))) short  short8;  // raw 16B
typedef __attribute__((ext_vector_type(4))) float  f32x4;

static __device__ __forceinline__ float fast_exp2(float x) {
#if __has_builtin(__builtin_amdgcn_exp2f)
    return __builtin_amdgcn_exp2f(x);
#else
    return exp2f(x);
#endif
}

// Async global->LDS DMA, 16B per lane (global_load_lds_dwordx4).
static __device__ __forceinline__ void gload_lds16(
    const _Float16* __restrict__ g, _Float16* l)
{
    __builtin_amdgcn_global_load_lds(
        (const __attribute__((address_space(1))) void*)g,
        (__attribute__((address_space(3))) void*)l, 16, 0, 0);
}

// ---------------------------------------------------------------------------
// Fused prep -- fp32->fp16 convert of x/ctx (blocks 0..6143) AND the 4
// weight transposes (blocks 6144..6719).  Wk carries 0.125*log2e.
// (unchanged from R8)
// ---------------------------------------------------------------------------
__global__ __launch_bounds__(256) void prep_fused(
    const float* __restrict__ x, const float* __restrict__ ctx,
    _Float16* __restrict__ xh, _Float16* __restrict__ ch, int n,
    const float* __restrict__ Wq, const float* __restrict__ Wk,
    const float* __restrict__ Wv, const float* __restrict__ Wo,
    _Float16* __restrict__ WqT, _Float16* __restrict__ WkT,
    _Float16* __restrict__ WvT, _Float16* __restrict__ WoT)
{
    __shared__ float tile[64][65];
    const int bid = blockIdx.x;

    if (bid < 6144) {
        const float* in = (bid >= 3072) ? ctx : x;
        _Float16* out   = (bid >= 3072) ? ch  : xh;
        int bb2 = (bid >= 3072) ? bid - 3072 : bid;
        int i = (bb2 * 256 + threadIdx.x) * 8;
        if (i < n) {
            float4 v0 = *(const float4*)(in + i);
            float4 v1 = *(const float4*)(in + i + 4);
            hv8 h = { (_Float16)v0.x, (_Float16)v0.y, (_Float16)v0.z, (_Float16)v0.w,
                      (_Float16)v1.x, (_Float16)v1.y, (_Float16)v1.z, (_Float16)v1.w };
            *(hv8*)(out + i) = h;
        }
        return;
    }

    const int t  = bid - 6144;            // 0..575
    const int z  = t / 144;
    const int rm = t - z * 144;
    const int by = rm / 12, bx = rm - by * 12;

    const float* W = (z == 0) ? Wq : (z == 1) ? Wk : (z == 2) ? Wv : Wo;
    _Float16*   WT = (z == 0) ? WqT : (z == 1) ? WkT : (z == 2) ? WvT : WoT;
    const float scale = (z == 1) ? 0.125f * LOG2E : 1.0f;

    const int tx = threadIdx.x & 15, ty = threadIdx.x >> 4;
    const int n0 = bx * 64, k0 = by * 64;

    #pragma unroll
    for (int ii = 0; ii < 4; ++ii) {
        int k = ty + ii * 16;
        float4 v = *(const float4*)(W + (size_t)(k0 + k) * CC + n0 + tx * 4);
        tile[k][tx*4+0] = v.x; tile[k][tx*4+1] = v.y;
        tile[k][tx*4+2] = v.z; tile[k][tx*4+3] = v.w;
    }
    __syncthreads();
    #pragma unroll
    for (int ii = 0; ii < 4; ++ii) {
        int nn = ty + ii * 16;
        _Float16* dst = WT + (size_t)(n0 + nn) * CC + k0 + tx * 4;
        dst[0] = (_Float16)(tile[tx*4+0][nn] * scale);
        dst[1] = (_Float16)(tile[tx*4+1][nn] * scale);
        dst[2] = (_Float16)(tile[tx*4+2][nn] * scale);
        dst[3] = (_Float16)(tile[tx*4+3][nn] * scale);
    }
}

// ---------------------------------------------------------------------------
// R9: fused QKV GEMM, grid 768 = EXACTLY 3 blocks/CU (was 1152 = 4.5).
//   z2=0 blocks: Q = xh @ WqT^T (as before).
//   z2=1 blocks: K AND V computed together off ONE staged A=ch tile --
//     the old kernel staged the same ch panel twice (z=1 and z=2).
//     Per kt: 12 DMA (A,Bk,Bv) + 64 MFMA vs old 2x(8 DMA + 32 MFMA):
//     -25% staged bytes, 1.8x MFMA:stage density, half the barrier count
//     per output element.
//   Mapping t = xcd*96 + idx, z2 = t&1: bijective, each XCD gets 48 Q + 48
//   KV blocks and a contiguous by-range (A-panel L2 locality).
//   __launch_bounds__(256,3) caps VGPRs ~170 so dual acc (128 VGPR) keeps
//   3 blocks/CU (LDS 48KB -> 3/CU is the binding limit anyway).
// ---------------------------------------------------------------------------
__global__ __launch_bounds__(256, 3) void gemm_qkv_f(
    const _Float16* __restrict__ xh, const _Float16* __restrict__ ch,
    const _Float16* __restrict__ WqT, const _Float16* __restrict__ WkT,
    const _Float16* __restrict__ WvT,
    _Float16* __restrict__ Qh, _Float16* __restrict__ Kh,
    _Float16* __restrict__ Vt)
{
    const int bid = blockIdx.x;
    const int t   = (bid & 7) * 96 + (bid >> 3);   // bijective 0..767
    const int z2  = t & 1;                          // 0 = Q, 1 = K+V
    const int u   = t >> 1;                         // 0..383
    const int by  = u / 6, bx = u - by * 6;

    __shared__ _Float16 smem[3 * 128 * 64];   // sA | sB0 | sB1 ; epi: sT[128][137]
    _Float16* sA  = smem;
    _Float16* sB0 = smem + 8192;
    _Float16* sB1 = smem + 16384;

    const int tid  = threadIdx.x;
    const int wave = tid >> 6, lane = tid & 63;
    const int quad = lane >> 4, l16 = lane & 15;
    const int m0 = by * 128, n0 = bx * 128;
    const int mw = (wave & 1) * 64, nw = (wave >> 1) * 64;

    const int srow = wave * 32 + (lane >> 3);
    const int scol = (lane & 7) * 8;

    const _Float16* A  = z2 ? ch  : xh;
    const _Float16* B0 = z2 ? WkT : WqT;

    f32x4 acc0[4][4], acc1[4][4];
    #pragma unroll
    for (int i = 0; i < 4; ++i)
        #pragma unroll
        for (int j = 0; j < 4; ++j) {
            acc0[i][j] = (f32x4){0.f,0.f,0.f,0.f};
            acc1[i][j] = (f32x4){0.f,0.f,0.f,0.f};
        }

    for (int kt = 0; kt < CC; kt += 64) {
        #pragma unroll
        for (int i = 0; i < 4; ++i) {
            gload_lds16(A  + (size_t)(m0 + srow + i*8) * CC + kt + scol,
                        &sA [(wave*32 + i*8) * 64]);
            gload_lds16(B0 + (size_t)(n0 + srow + i*8) * CC + kt + scol,
                        &sB0[(wave*32 + i*8) * 64]);
        }
        if (z2) {
            #pragma unroll
            for (int i = 0; i < 4; ++i)
                gload_lds16(WvT + (size_t)(n0 + srow + i*8) * CC + kt + scol,
                            &sB1[(wave*32 + i*8) * 64]);
        }
        __syncthreads();
        #pragma unroll
        for (int kk = 0; kk < 2; ++kk) {
            hv8 af[4];
            #pragma unroll
            for (int mi = 0; mi < 4; ++mi)
                af[mi] = *(const hv8*)&sA[(mw + mi*16 + l16)*64 + kk*32 + quad*8];
            {
                hv8 bf[4];
                #pragma unroll
                for (int nj = 0; nj < 4; ++nj)
                    bf[nj] = *(const hv8*)&sB0[(nw + nj*16 + l16)*64 + kk*32 + quad*8];
                #pragma unroll
                for (int mi = 0; mi < 4; ++mi)
                    #pragma unroll
                    for (int nj = 0; nj < 4; ++nj)
                        acc0[mi][nj] = __builtin_amdgcn_mfma_f32_16x16x32_f16(
                            af[mi], bf[nj], acc0[mi][nj], 0, 0, 0);
            }
            if (z2) {
                hv8 bf[4];
                #pragma unroll
                for (int nj = 0; nj < 4; ++nj)
                    bf[nj] = *(const hv8*)&sB1[(nw + nj*16 + l16)*64 + kk*32 + quad*8];
                #pragma unroll
                for (int mi = 0; mi < 4; ++mi)
                    #pragma unroll
                    for (int nj = 0; nj < 4; ++nj)
                        acc1[mi][nj] = __builtin_amdgcn_mfma_f32_16x16x32_f16(
                            af[mi], bf[nj], acc1[mi][nj], 0, 0, 0);
            }
        }
        __syncthreads();
    }

    _Float16* sT = smem;   // [128][137] = 17536 halves, fits in 24576

    // ---- output 0: Q (z2=0) or K (z2=1), head-major [b,h,t,d]
    {
        _Float16* C0 = z2 ? Kh : Qh;
        #pragma unroll
        for (int mi = 0; mi < 4; ++mi)
            #pragma unroll
            for (int nj = 0; nj < 4; ++nj)
                #pragma unroll
                for (int r = 0; r < 4; ++r)
                    sT[(mw + mi*16 + quad*4 + r)*137 + nw + nj*16 + l16] =
                        (_Float16)acc0[mi][nj][r];
        __syncthreads();
        #pragma unroll
        for (int ii = 0; ii < 8; ++ii) {
            int uu = tid + ii * 256;
            int row = uu >> 4;
            int chk = uu & 15;
            hv8 o;
            #pragma unroll
            for (int j = 0; j < 8; ++j) o[j] = sT[row*137 + chk*8 + j];
            int gm = m0 + row, gn = n0 + chk*8;
            int bI = gm >> 10, tI = gm & 1023;
            int hI = gn >> 6,  dI = gn & 63;
            *(hv8*)(C0 + (((size_t)bI * NH + hI) * TT + tI) * HD + dI) = o;
        }
    }

    // ---- output 1 (z2=1 only): V transposed [b,h,d,t]
    if (z2) {
        __syncthreads();   // all sT reads above done before rewrite
        #pragma unroll
        for (int mi = 0; mi < 4; ++mi)
            #pragma unroll
            for (int nj = 0; nj < 4; ++nj)
                #pragma unroll
                for (int r = 0; r < 4; ++r)
                    sT[(mw + mi*16 + quad*4 + r)*137 + nw + nj*16 + l16] =
                        (_Float16)acc1[mi][nj][r];
        __syncthreads();
        #pragma unroll
        for (int ii = 0; ii < 8; ++ii) {
            int uu = tid + ii * 256;
            int dloc = uu >> 4;
            int tch  = uu & 15;
            hv8 o;
            #pragma unroll
            for (int j = 0; j < 8; ++j) o[j] = sT[(tch*8 + j)*137 + dloc];
            int gn = n0 + dloc;
            int hI = gn >> 6, dI = gn & 63;
            int gm = m0 + tch * 8;
            int bI = gm >> 10, tI = gm & 1023;
            *(hv8*)(Vt + (((size_t)bI * NH + hI) * HD + dI) * TT + tI) = o;
        }
    }
}

// ---------------------------------------------------------------------------
// fp16 single-pass output GEMM (unchanged from R5).
// ---------------------------------------------------------------------------
__global__ __launch_bounds__(256) void gemm_out_f16(
    const _Float16* __restrict__ A, const _Float16* __restrict__ BT,
    const float* __restrict__ bias, float* __restrict__ out)
{
    __shared__ _Float16 sA[128 * 64];
    __shared__ _Float16 sB[64 * 64];

    const int bid = blockIdx.x;
    const int lid = (bid & 7) * 96 + (bid >> 3);
    const int by  = lid / 12;
    const int bx  = lid - by * 12;

    const int tid  = threadIdx.x;
    const int wave = tid >> 6, lane = tid & 63;
    const int quad = lane >> 4, l16 = lane & 15;
    const int m0 = by * 128, n0 = bx * 64;
    const int mw = (wave & 1) * 64, nw = (wave >> 1) * 32;

    const int srow = lane >> 3;
    const int scol = (lane & 7) * 8;

    f32x4 acc[4][2];
    #pragma unroll
    for (int i = 0; i < 4; ++i)
        #pragma unroll
        for (int j = 0; j < 2; ++j) acc[i][j] = (f32x4){0.f,0.f,0.f,0.f};

    for (int kt = 0; kt < CC; kt += 64) {
        #pragma unroll
        for (int i = 0; i < 4; ++i)
            gload_lds16(A + (size_t)(m0 + wave*32 + i*8 + srow) * CC + kt + scol,
                        &sA[(wave*32 + i*8) * 64]);
        #pragma unroll
        for (int i = 0; i < 2; ++i)
            gload_lds16(BT + (size_t)(n0 + wave*16 + i*8 + srow) * CC + kt + scol,
                        &sB[(wave*16 + i*8) * 64]);
        __syncthreads();
        #pragma unroll
        for (int kk = 0; kk < 2; ++kk) {
            hv8 af[4], bf[2];
            #pragma unroll
            for (int mi = 0; mi < 4; ++mi)
                af[mi] = *(const hv8*)&sA[(mw + mi*16 + l16)*64 + kk*32 + quad*8];
            #pragma unroll
            for (int nj = 0; nj < 2; ++nj)
                bf[nj] = *(const hv8*)&sB[(nw + nj*16 + l16)*64 + kk*32 + quad*8];
            #pragma unroll
            for (int mi = 0; mi < 4; ++mi)
                #pragma unroll
                for (int nj = 0; nj < 2; ++nj)
                    acc[mi][nj] = __builtin_amdgcn_mfma_f32_16x16x32_f16(
                        af[mi], bf[nj], acc[mi][nj], 0, 0, 0);
        }
        __syncthreads();
    }

    #pragma unroll
    for (int mi = 0; mi < 4; ++mi)
        #pragma unroll
        for (int nj = 0; nj < 2; ++nj)
            #pragma unroll
            for (int r = 0; r < 4; ++r) {
                int gm = m0 + mw + mi*16 + quad*4 + r;
                int gn = n0 + nw + nj*16 + l16;
                out[(size_t)gm * CC + gn] = acc[mi][nj][r] + bias[gn];
            }
}

// ---------------------------------------------------------------------------
// fp16 MFMA flash attention (unchanged from R8: swapped QK^T, register-P via
// permlane repack, K/V double-buffer, 1 barrier/kt, XCD swizzle).
// ---------------------------------------------------------------------------
#define KOFFB(b) ((b)*9216)          // K tile of buf b (halves)
#define VOFFB(b) ((b)*9216 + 4608)   // V tile of buf b

__global__ __launch_bounds__(256) void attn_mfma(
    const _Float16* __restrict__ Q, const _Float16* __restrict__ K,
    const _Float16* __restrict__ Vt, const float* __restrict__ relh,
    const float* __restrict__ relw, _Float16* __restrict__ O)
{
    __shared__ _Float16 sKV[18432];     // 2 dbuf x {K[64][72], V[64][72]}
    __shared__ _Float16 sH [128][34];   // rh table [qi][hk]

    const int tid  = threadIdx.x;
    const int wave = tid >> 6, lane = tid & 63;
    const int quad = lane >> 4, l16 = lane & 15;

    const int bid = blockIdx.x;
    const int idx = bid >> 3;
    const int qt  = idx & 7;
    const int bh  = (bid & 7) + 8 * (idx >> 3);
    const int h   = bh % NH;
    const int b   = bh / NH;
    const size_t hbase = ((size_t)b * NH + h) * TT * HD;

    short8 pK[2], pV[2];
    auto loadKV = [&](int kt) {
        #pragma unroll
        for (int ii = 0; ii < 2; ++ii) {
            int u = tid + ii * 256;
            int row = u >> 3, c8 = u & 7;
            pK[ii] = *(const short8*)(K  + hbase + (size_t)(kt*64 + row) * HD + c8*8);
            pV[ii] = *(const short8*)(Vt + hbase + (size_t)row * TT + kt*64 + c8*8);
        }
    };
    auto writeKV = [&](int bf) {
        #pragma unroll
        for (int ii = 0; ii < 2; ++ii) {
            int u = tid + ii * 256;
            int row = u >> 3, c8 = u & 7;
            *(short8*)&sKV[KOFFB(bf) + row*72 + c8*8] = pK[ii];
            *(short8*)&sKV[VOFFB(bf) + row*72 + c8*8] = pV[ii];
        }
    };

    #pragma unroll
    for (int ii = 0; ii < 4; ++ii) {
        int u = tid + ii * 256;
        int row = u >> 3, c8 = u & 7;
        *(short8*)&sKV[row*72 + c8*8] =
            *(const short8*)(Q + hbase + (size_t)(qt*128 + row) * HD + c8*8);
    }
    #pragma unroll
    for (int ii = 0; ii < 2; ++ii) {
        int u = tid + ii * 256;
        if (u < 280) {                 // 35 rows x 8 chunks of relh window
            int row = u >> 3, c8 = u & 7;
            const float* src = relh + (size_t)(4*qt + row) * HD + c8*8;
            float4 v0 = *(const float4*)(src);
            float4 v1 = *(const float4*)(src + 4);
            hv8 s = { (_Float16)(v0.x*LOG2E), (_Float16)(v0.y*LOG2E),
                      (_Float16)(v0.z*LOG2E), (_Float16)(v0.w*LOG2E),
                      (_Float16)(v1.x*LOG2E), (_Float16)(v1.y*LOG2E),
                      (_Float16)(v1.z*LOG2E), (_Float16)(v1.w*LOG2E) };
            *(hv8*)&sKV[9216 + row*72 + c8*8] = s;
        }
    }
    #pragma unroll
    for (int ii = 0; ii < 2; ++ii) {
        int u = tid + ii * 256;
        int row = u >> 3, c8 = u & 7;
        int sr = row < 63 ? row : 62;
        const float* src = relw + (size_t)sr * HD + c8*8;
        float4 v0 = *(const float4*)(src);
        float4 v1 = *(const float4*)(src + 4);
        hv8 s = { (_Float16)(v0.x*LOG2E), (_Float16)(v0.y*LOG2E),
                  (_Float16)(v0.z*LOG2E), (_Float16)(v0.w*LOG2E),
                  (_Float16)(v1.x*LOG2E), (_Float16)(v1.y*LOG2E),
                  (_Float16)(v1.z*LOG2E), (_Float16)(v1.w*LOG2E) };
        *(hv8*)&sKV[13824 + row*72 + c8*8] = s;
    }
    loadKV(0);
    __syncthreads();

    hv8 aQ0[2], aQ1[2];
    #pragma unroll
    for (int g = 0; g < 2; ++g) {
        int qrow = wave*32 + g*16 + l16;
        aQ0[g] = *(const hv8*)&sKV[qrow*72 + quad*8];
        aQ1[g] = *(const hv8*)&sKV[qrow*72 + 32 + quad*8];
    }
    __syncthreads();

    #pragma unroll
    for (int g = 0; g < 2; ++g)
        #pragma unroll
        for (int t = 0; t < 2; ++t) {
            int wr = wave + 31 - (t*16 + l16);
            hv8 b0 = *(const hv8*)&sKV[9216 + wr*72 + quad*8];
            hv8 b1 = *(const hv8*)&sKV[9216 + wr*72 + 32 + quad*8];
            f32x4 c = {0.f,0.f,0.f,0.f};
            c = __builtin_amdgcn_mfma_f32_16x16x32_f16(aQ0[g], b0, c, 0, 0, 0);
            c = __builtin_amdgcn_mfma_f32_16x16x32_f16(aQ1[g], b1, c, 0, 0, 0);
            #pragma unroll
            for (int r = 0; r < 4; ++r)
                sH[wave*32 + g*16 + quad*4 + r][t*16 + l16] = (_Float16)c[r];
        }
    #pragma unroll
    for (int g = 0; g < 2; ++g)
        #pragma unroll
        for (int t = 0; t < 4; ++t) {
            hv8 b0 = *(const hv8*)&sKV[13824 + (t*16 + l16)*72 + quad*8];
            hv8 b1 = *(const hv8*)&sKV[13824 + (t*16 + l16)*72 + 32 + quad*8];
            f32x4 c = {0.f,0.f,0.f,0.f};
            c = __builtin_amdgcn_mfma_f32_16x16x32_f16(aQ0[g], b0, c, 0, 0, 0);
            c = __builtin_amdgcn_mfma_f32_16x16x32_f16(aQ1[g], b1, c, 0, 0, 0);
            #pragma unroll
            for (int r = 0; r < 4; ++r)
                sKV[wave*2304 + (g*16 + quad*4 + r)*72 + t*16 + l16] = (_Float16)c[r];
        }
    float rwSw[2][2][4];
    #pragma unroll
    for (int g = 0; g < 2; ++g)
        #pragma unroll
        for (int j = 0; j < 2; ++j)
            #pragma unroll
            for (int r = 0; r < 4; ++r) {
                int q32 = g*16 + l16;
                int w   = q32 - j*16 - quad*4 - r + 31;   // 0..62
                rwSw[g][j][r] = (float)sKV[wave*2304 + q32*72 + w];
            }
    __syncthreads();
    writeKV(0);
    loadKV(1);
    __syncthreads();

    f32x4 o[2][4];
    #pragma unroll
    for (int g = 0; g < 2; ++g)
        #pragma unroll
        for (int n = 0; n < 4; ++n) o[g][n] = (f32x4){0.f,0.f,0.f,0.f};
    f32x4 lacc[2] = { (f32x4){0.f,0.f,0.f,0.f}, (f32x4){0.f,0.f,0.f,0.f} };
    const hv8 vone = { (_Float16)1.f, (_Float16)1.f, (_Float16)1.f, (_Float16)1.f,
                       (_Float16)1.f, (_Float16)1.f, (_Float16)1.f, (_Float16)1.f };

    for (int kt = 0; kt < 16; ++kt) {
        const int buf = kt & 1;
        if (kt < 15) writeKV(buf ^ 1);
        if (kt < 14) loadKV(kt + 2);

        float rhq[2][2];
        #pragma unroll
        for (int g = 0; g < 2; ++g) {
            unsigned pr = *(const unsigned*)&sH[wave*32 + g*16 + l16][kt*2];
            rhq[g][0] = (float)(*(const _Float16*)&pr);
            rhq[g][1] = (float)(*((const _Float16*)&pr + 1));
        }

        unsigned wpk[2][4][2];
        #pragma unroll
        for (int bb = 0; bb < 4; ++bb) {
            hv8 bK0 = *(const hv8*)&sKV[KOFFB(buf) + (bb*16 + l16)*72 + quad*8];
            hv8 bK1 = *(const hv8*)&sKV[KOFFB(buf) + (bb*16 + l16)*72 + 32 + quad*8];
            #pragma unroll
            for (int g = 0; g < 2; ++g) {
                f32x4 c;
                #pragma unroll
                for (int r = 0; r < 4; ++r)
                    c[r] = rhq[g][bb>>1] + rwSw[g][bb&1][r];
                c = __builtin_amdgcn_mfma_f32_16x16x32_f16(bK0, aQ0[g], c, 0, 0, 0);
                c = __builtin_amdgcn_mfma_f32_16x16x32_f16(bK1, aQ1[g], c, 0, 0, 0);
                #pragma unroll
                for (int rr = 0; rr < 2; ++rr) {
                    union { _Float16 hh[2]; unsigned u; } pu;
                    pu.hh[0] = (_Float16)fast_exp2(c[2*rr]);
                    pu.hh[1] = (_Float16)fast_exp2(c[2*rr+1]);
                    wpk[g][bb][rr] = pu.u;
                }
            }
        }

        hv8 aP[2][2];
        #pragma unroll
        for (int g = 0; g < 2; ++g)
            #pragma unroll
            for (int kk = 0; kk < 2; ++kk) {
                union { unsigned u4[4]; hv8 v; } cv;
                #pragma unroll
                for (int rr = 0; rr < 2; ++rr) {
                    unsigned e = wpk[g][2*kk][rr];
                    unsigned oo = wpk[g][2*kk+1][rr];
                    asm("v_permlane32_swap_b32 %0, %1" : "+v"(e), "+v"(oo));
                    asm("v_permlane16_swap_b32 %0, %1" : "+v"(e), "+v"(oo));
                    cv.u4[rr]     = e;
                    cv.u4[2 + rr] = oo;
                }
                aP[g][kk] = cv.v;
            }

        __builtin_amdgcn_s_setprio(1);
        #pragma unroll
        for (int g = 0; g < 2; ++g) {
            lacc[g] = __builtin_amdgcn_mfma_f32_16x16x32_f16(aP[g][0], vone, lacc[g], 0, 0, 0);
            lacc[g] = __builtin_amdgcn_mfma_f32_16x16x32_f16(aP[g][1], vone, lacc[g], 0, 0, 0);
        }
        #pragma unroll
        for (int nn = 0; nn < 4; ++nn) {
            hv8 bV0 = *(const hv8*)&sKV[VOFFB(buf) + (nn*16 + l16)*72 + quad*8];
            hv8 bV1 = *(const hv8*)&sKV[VOFFB(buf) + (nn*16 + l16)*72 + 32 + quad*8];
            #pragma unroll
            for (int g = 0; g < 2; ++g) {
                o[g][nn] = __builtin_amdgcn_mfma_f32_16x16x32_f16(aP[g][0], bV0, o[g][nn], 0, 0, 0);
                o[g][nn] = __builtin_amdgcn_mfma_f32_16x16x32_f16(aP[g][1], bV1, o[g][nn], 0, 0, 0);
            }
        }
        __builtin_amdgcn_s_setprio(0);

        __syncthreads();
    }

    #pragma unroll
    for (int g = 0; g < 2; ++g) {
        float inv[4];
        #pragma unroll
        for (int r = 0; r < 4; ++r) inv[r] = 1.f / lacc[g][r];
        #pragma unroll
        for (int n = 0; n < 4; ++n)
            #pragma unroll
            for (int r = 0; r < 4; ++r) {
                int t = qt*128 + wave*32 + g*16 + quad*4 + r;
                size_t addr = ((size_t)b * TT + t) * CC + h*HD + n*16 + l16;
                O[addr] = (_Float16)(o[g][n][r] * inv[r]);
            }
    }
}

// ---------------------------------------------------------------------------
extern "C" void kernel_launch(void* const* d_in, const int* in_sizes, int n_in,
                              void* d_out, int out_size, void* d_ws, size_t ws_size,
                              hipStream_t stream) {
    const float* x   = (const float*)d_in[0];
    const float* ctx = (const float*)d_in[1];
    const float* Wq  = (const float*)d_in[2];
    const float* Wk  = (const float*)d_in[3];
    const float* Wv  = (const float*)d_in[4];
    const float* Wo  = (const float*)d_in[5];
    const float* bo  = (const float*)d_in[6];
    const float* rh  = (const float*)d_in[7];
    const float* rw  = (const float*)d_in[8];
    float* out = (float*)d_out;

    const size_t MN = (size_t)BB * TT * CC;   // 6291456
    const size_t WN = (size_t)CC * CC;        // 589824
    _Float16* p = (_Float16*)d_ws;
    _Float16* xh  = p; p += MN;
    _Float16* ch  = p; p += MN;
    _Float16* WqT = p; p += WN;
    _Float16* WkT = p; p += WN;
    _Float16* WvT = p; p += WN;
    _Float16* WoT = p; p += WN;
    _Float16* Qh  = p; p += MN;
    _Float16* Kh  = p; p += MN;
    _Float16* VtB = p; p += MN;
    _Float16* Oh  = p; p += MN;

    dim3 blk(256);

    prep_fused<<<dim3(6720), blk, 0, stream>>>(
        x, ctx, xh, ch, (int)MN, Wq, Wk, Wv, Wo, WqT, WkT, WvT, WoT);

    gemm_qkv_f<<<dim3(768), blk, 0, stream>>>(
        xh, ch, WqT, WkT, WvT, Qh, Kh, VtB);

    attn_mfma<<<dim3(BB*NH*(TT/128)), blk, 0, stream>>>(
        Qh, Kh, VtB, rh, rw, Oh);

    gemm_out_f16<<<dim3(768), blk, 0, stream>>>(
        Oh, WoT, bo, out);
}

// Round 10
// 238.498 us; speedup vs baseline: 1.2975x; 1.2975x over previous
//
#include <hip/hip_runtime.h>
#include <math.h>

#define BB 8
#define TT 1024
#define CC 768
#define NH 12
#define HD 64
#define LOG2E 1.44269504088896f

typedef __attribute__((ext_vector_type(8))) _Float16 hv8;   // 8 fp16 (4 VGPRs)
typedef __attribute__((ext_vector_type(8))) short  short8;  // raw 16B
typedef __attribute__((ext_vector_type(4))) float  f32x4;

static __device__ __forceinline__ float fast_exp2(float x) {
#if __has_builtin(__builtin_amdgcn_exp2f)
    return __builtin_amdgcn_exp2f(x);
#else
    return exp2f(x);
#endif
}

// Async global->LDS DMA, 16B per lane (global_load_lds_dwordx4).
static __device__ __forceinline__ void gload_lds16(
    const _Float16* __restrict__ g, _Float16* l)
{
    __builtin_amdgcn_global_load_lds(
        (const __attribute__((address_space(1))) void*)g,
        (__attribute__((address_space(3))) void*)l, 16, 0, 0);
}

// ---------------------------------------------------------------------------
// Fused prep -- fp32->fp16 convert of x/ctx (blocks 0..6143) AND the 4
// weight transposes (blocks 6144..6719).  Wk carries 0.125*log2e.
// (unchanged from R8)
// ---------------------------------------------------------------------------
__global__ __launch_bounds__(256) void prep_fused(
    const float* __restrict__ x, const float* __restrict__ ctx,
    _Float16* __restrict__ xh, _Float16* __restrict__ ch, int n,
    const float* __restrict__ Wq, const float* __restrict__ Wk,
    const float* __restrict__ Wv, const float* __restrict__ Wo,
    _Float16* __restrict__ WqT, _Float16* __restrict__ WkT,
    _Float16* __restrict__ WvT, _Float16* __restrict__ WoT)
{
    __shared__ float tile[64][65];
    const int bid = blockIdx.x;

    if (bid < 6144) {
        const float* in = (bid >= 3072) ? ctx : x;
        _Float16* out   = (bid >= 3072) ? ch  : xh;
        int bb2 = (bid >= 3072) ? bid - 3072 : bid;
        int i = (bb2 * 256 + threadIdx.x) * 8;
        if (i < n) {
            float4 v0 = *(const float4*)(in + i);
            float4 v1 = *(const float4*)(in + i + 4);
            hv8 h = { (_Float16)v0.x, (_Float16)v0.y, (_Float16)v0.z, (_Float16)v0.w,
                      (_Float16)v1.x, (_Float16)v1.y, (_Float16)v1.z, (_Float16)v1.w };
            *(hv8*)(out + i) = h;
        }
        return;
    }

    const int t  = bid - 6144;            // 0..575
    const int z  = t / 144;
    const int rm = t - z * 144;
    const int by = rm / 12, bx = rm - by * 12;

    const float* W = (z == 0) ? Wq : (z == 1) ? Wk : (z == 2) ? Wv : Wo;
    _Float16*   WT = (z == 0) ? WqT : (z == 1) ? WkT : (z == 2) ? WvT : WoT;
    const float scale = (z == 1) ? 0.125f * LOG2E : 1.0f;

    const int tx = threadIdx.x & 15, ty = threadIdx.x >> 4;
    const int n0 = bx * 64, k0 = by * 64;

    #pragma unroll
    for (int ii = 0; ii < 4; ++ii) {
        int k = ty + ii * 16;
        float4 v = *(const float4*)(W + (size_t)(k0 + k) * CC + n0 + tx * 4);
        tile[k][tx*4+0] = v.x; tile[k][tx*4+1] = v.y;
        tile[k][tx*4+2] = v.z; tile[k][tx*4+3] = v.w;
    }
    __syncthreads();
    #pragma unroll
    for (int ii = 0; ii < 4; ++ii) {
        int nn = ty + ii * 16;
        _Float16* dst = WT + (size_t)(n0 + nn) * CC + k0 + tx * 4;
        dst[0] = (_Float16)(tile[tx*4+0][nn] * scale);
        dst[1] = (_Float16)(tile[tx*4+1][nn] * scale);
        dst[2] = (_Float16)(tile[tx*4+2][nn] * scale);
        dst[3] = (_Float16)(tile[tx*4+3][nn] * scale);
    }
}

// ---------------------------------------------------------------------------
// Fused QKV GEMM -- R10: REVERT to R8's proven single-accumulator kernel
// (R9's dual-acc fusion spilled: VGPR_Count 84 < 128 needed, WRITE_SIZE
// 97MB = outputs + ~60MB scratch, 138us/dispatch).  One change vs R8:
// XCD decode now gives XCD i the full by-range [8i,8i+8) across ALL of
// Q/K/V -- K-blocks and V-blocks reading the same ch A-panel were 384
// lids apart (different XCDs) in R8; now they share one XCD's L2
// (per XCD: 1.6MB x-rows + 1.6MB ctx-rows + 3.5MB weights ~ L2-resident).
// ---------------------------------------------------------------------------
__global__ __launch_bounds__(256) void gemm_qkv3(
    const _Float16* __restrict__ xh, const _Float16* __restrict__ ch,
    const _Float16* __restrict__ WqT, const _Float16* __restrict__ WkT,
    const _Float16* __restrict__ WvT,
    _Float16* __restrict__ Qh, _Float16* __restrict__ Kh,
    _Float16* __restrict__ Vt)
{
    // bijective: (xcd, local) -> (by, z, bx); by-range is XCD-local.
    const int bid   = blockIdx.x;
    const int xcd   = bid & 7;
    const int local = bid >> 3;             // 0..143
    const int byl   = local / 18;           // 0..7
    const int rr    = local - byl * 18;     // 0..17
    const int z     = (rr < 6) ? 0 : ((rr < 12) ? 1 : 2);
    const int bx    = (rr < 6) ? rr : ((rr < 12) ? rr - 6 : rr - 12);
    const int by    = xcd * 8 + byl;        // 0..63

    const _Float16* A  = (z == 0) ? xh : ch;
    const _Float16* BT = (z == 0) ? WqT : (z == 1) ? WkT : WvT;

    __shared__ _Float16 smem[128 * 137];
    _Float16* sA = smem;
    _Float16* sB = smem + 128 * 64;

    const int tid  = threadIdx.x;
    const int wave = tid >> 6, lane = tid & 63;
    const int quad = lane >> 4, l16 = lane & 15;
    const int m0 = by * 128, n0 = bx * 128;
    const int mw = (wave & 1) * 64, nw = (wave >> 1) * 64;

    const int srow = wave * 32 + (lane >> 3);
    const int scol = (lane & 7) * 8;

    f32x4 acc[4][4];
    #pragma unroll
    for (int i = 0; i < 4; ++i)
        #pragma unroll
        for (int j = 0; j < 4; ++j) acc[i][j] = (f32x4){0.f,0.f,0.f,0.f};

    for (int kt = 0; kt < CC; kt += 64) {
        #pragma unroll
        for (int i = 0; i < 4; ++i) {
            gload_lds16(A  + (size_t)(m0 + srow + i*8) * CC + kt + scol,
                        &sA[(wave*32 + i*8) * 64]);
            gload_lds16(BT + (size_t)(n0 + srow + i*8) * CC + kt + scol,
                        &sB[(wave*32 + i*8) * 64]);
        }
        __syncthreads();
        #pragma unroll
        for (int kk = 0; kk < 2; ++kk) {
            hv8 af[4], bf[4];
            #pragma unroll
            for (int mi = 0; mi < 4; ++mi)
                af[mi] = *(const hv8*)&sA[(mw + mi*16 + l16)*64 + kk*32 + quad*8];
            #pragma unroll
            for (int nj = 0; nj < 4; ++nj)
                bf[nj] = *(const hv8*)&sB[(nw + nj*16 + l16)*64 + kk*32 + quad*8];
            #pragma unroll
            for (int mi = 0; mi < 4; ++mi)
                #pragma unroll
                for (int nj = 0; nj < 4; ++nj)
                    acc[mi][nj] = __builtin_amdgcn_mfma_f32_16x16x32_f16(
                        af[mi], bf[nj], acc[mi][nj], 0, 0, 0);
        }
        __syncthreads();
    }

    if (z < 2) {
        _Float16* Chead = (z == 0) ? Qh : Kh;
        _Float16* sT = smem;   // [128][137]
        #pragma unroll
        for (int mi = 0; mi < 4; ++mi)
            #pragma unroll
            for (int nj = 0; nj < 4; ++nj)
                #pragma unroll
                for (int r = 0; r < 4; ++r)
                    sT[(mw + mi*16 + quad*4 + r)*137 + nw + nj*16 + l16] =
                        (_Float16)acc[mi][nj][r];
        __syncthreads();
        #pragma unroll
        for (int ii = 0; ii < 8; ++ii) {
            int u = tid + ii * 256;
            int row = u >> 4;
            int chk = u & 15;
            hv8 o;
            #pragma unroll
            for (int j = 0; j < 8; ++j) o[j] = sT[row*137 + chk*8 + j];
            int gm = m0 + row, gn = n0 + chk*8;
            int bI = gm >> 10, tI = gm & 1023;
            int hI = gn >> 6,  dI = gn & 63;
            *(hv8*)(Chead + (((size_t)bI * NH + hI) * TT + tI) * HD + dI) = o;
        }
    } else {
        _Float16* sT = smem;   // [128][137]
        #pragma unroll
        for (int mi = 0; mi < 4; ++mi)
            #pragma unroll
            for (int nj = 0; nj < 4; ++nj)
                #pragma unroll
                for (int r = 0; r < 4; ++r)
                    sT[(mw + mi*16 + quad*4 + r)*137 + nw + nj*16 + l16] =
                        (_Float16)acc[mi][nj][r];
        __syncthreads();
        #pragma unroll
        for (int ii = 0; ii < 8; ++ii) {
            int u = tid + ii * 256;
            int dloc = u >> 4;
            int tch  = u & 15;
            hv8 o;
            #pragma unroll
            for (int j = 0; j < 8; ++j) o[j] = sT[(tch*8 + j)*137 + dloc];
            int gn = n0 + dloc;
            int hI = gn >> 6, dI = gn & 63;
            int gm = m0 + tch * 8;
            int bI = gm >> 10, tI = gm & 1023;
            *(hv8*)(Vt + (((size_t)bI * NH + hI) * HD + dI) * TT + tI) = o;
        }
    }
}

// ---------------------------------------------------------------------------
// fp16 single-pass output GEMM (unchanged from R5).
// ---------------------------------------------------------------------------
__global__ __launch_bounds__(256) void gemm_out_f16(
    const _Float16* __restrict__ A, const _Float16* __restrict__ BT,
    const float* __restrict__ bias, float* __restrict__ out)
{
    __shared__ _Float16 sA[128 * 64];
    __shared__ _Float16 sB[64 * 64];

    const int bid = blockIdx.x;
    const int lid = (bid & 7) * 96 + (bid >> 3);
    const int by  = lid / 12;
    const int bx  = lid - by * 12;

    const int tid  = threadIdx.x;
    const int wave = tid >> 6, lane = tid & 63;
    const int quad = lane >> 4, l16 = lane & 15;
    const int m0 = by * 128, n0 = bx * 64;
    const int mw = (wave & 1) * 64, nw = (wave >> 1) * 32;

    const int srow = lane >> 3;
    const int scol = (lane & 7) * 8;

    f32x4 acc[4][2];
    #pragma unroll
    for (int i = 0; i < 4; ++i)
        #pragma unroll
        for (int j = 0; j < 2; ++j) acc[i][j] = (f32x4){0.f,0.f,0.f,0.f};

    for (int kt = 0; kt < CC; kt += 64) {
        #pragma unroll
        for (int i = 0; i < 4; ++i)
            gload_lds16(A + (size_t)(m0 + wave*32 + i*8 + srow) * CC + kt + scol,
                        &sA[(wave*32 + i*8) * 64]);
        #pragma unroll
        for (int i = 0; i < 2; ++i)
            gload_lds16(BT + (size_t)(n0 + wave*16 + i*8 + srow) * CC + kt + scol,
                        &sB[(wave*16 + i*8) * 64]);
        __syncthreads();
        #pragma unroll
        for (int kk = 0; kk < 2; ++kk) {
            hv8 af[4], bf[2];
            #pragma unroll
            for (int mi = 0; mi < 4; ++mi)
                af[mi] = *(const hv8*)&sA[(mw + mi*16 + l16)*64 + kk*32 + quad*8];
            #pragma unroll
            for (int nj = 0; nj < 2; ++nj)
                bf[nj] = *(const hv8*)&sB[(nw + nj*16 + l16)*64 + kk*32 + quad*8];
            #pragma unroll
            for (int mi = 0; mi < 4; ++mi)
                #pragma unroll
                for (int nj = 0; nj < 2; ++nj)
                    acc[mi][nj] = __builtin_amdgcn_mfma_f32_16x16x32_f16(
                        af[mi], bf[nj], acc[mi][nj], 0, 0, 0);
        }
        __syncthreads();
    }

    #pragma unroll
    for (int mi = 0; mi < 4; ++mi)
        #pragma unroll
        for (int nj = 0; nj < 2; ++nj)
            #pragma unroll
            for (int r = 0; r < 4; ++r) {
                int gm = m0 + mw + mi*16 + quad*4 + r;
                int gn = n0 + nw + nj*16 + l16;
                out[(size_t)gm * CC + gn] = acc[mi][nj][r] + bias[gn];
            }
}

// ---------------------------------------------------------------------------
// fp16 MFMA flash attention (unchanged from R8: swapped QK^T, register-P via
// permlane repack, K/V double-buffer, 1 barrier/kt, XCD swizzle).
// ---------------------------------------------------------------------------
#define KOFFB(b) ((b)*9216)          // K tile of buf b (halves)
#define VOFFB(b) ((b)*9216 + 4608)   // V tile of buf b

__global__ __launch_bounds__(256) void attn_mfma(
    const _Float16* __restrict__ Q, const _Float16* __restrict__ K,
    const _Float16* __restrict__ Vt, const float* __restrict__ relh,
    const float* __restrict__ relw, _Float16* __restrict__ O)
{
    __shared__ _Float16 sKV[18432];     // 2 dbuf x {K[64][72], V[64][72]}
    __shared__ _Float16 sH [128][34];   // rh table [qi][hk]

    const int tid  = threadIdx.x;
    const int wave = tid >> 6, lane = tid & 63;
    const int quad = lane >> 4, l16 = lane & 15;

    const int bid = blockIdx.x;
    const int idx = bid >> 3;
    const int qt  = idx & 7;
    const int bh  = (bid & 7) + 8 * (idx >> 3);
    const int h   = bh % NH;
    const int b   = bh / NH;
    const size_t hbase = ((size_t)b * NH + h) * TT * HD;

    short8 pK[2], pV[2];
    auto loadKV = [&](int kt) {
        #pragma unroll
        for (int ii = 0; ii < 2; ++ii) {
            int u = tid + ii * 256;
            int row = u >> 3, c8 = u & 7;
            pK[ii] = *(const short8*)(K  + hbase + (size_t)(kt*64 + row) * HD + c8*8);
            pV[ii] = *(const short8*)(Vt + hbase + (size_t)row * TT + kt*64 + c8*8);
        }
    };
    auto writeKV = [&](int bf) {
        #pragma unroll
        for (int ii = 0; ii < 2; ++ii) {
            int u = tid + ii * 256;
            int row = u >> 3, c8 = u & 7;
            *(short8*)&sKV[KOFFB(bf) + row*72 + c8*8] = pK[ii];
            *(short8*)&sKV[VOFFB(bf) + row*72 + c8*8] = pV[ii];
        }
    };

    #pragma unroll
    for (int ii = 0; ii < 4; ++ii) {
        int u = tid + ii * 256;
        int row = u >> 3, c8 = u & 7;
        *(short8*)&sKV[row*72 + c8*8] =
            *(const short8*)(Q + hbase + (size_t)(qt*128 + row) * HD + c8*8);
    }
    #pragma unroll
    for (int ii = 0; ii < 2; ++ii) {
        int u = tid + ii * 256;
        if (u < 280) {                 // 35 rows x 8 chunks of relh window
            int row = u >> 3, c8 = u & 7;
            const float* src = relh + (size_t)(4*qt + row) * HD + c8*8;
            float4 v0 = *(const float4*)(src);
            float4 v1 = *(const float4*)(src + 4);
            hv8 s = { (_Float16)(v0.x*LOG2E), (_Float16)(v0.y*LOG2E),
                      (_Float16)(v0.z*LOG2E), (_Float16)(v0.w*LOG2E),
                      (_Float16)(v1.x*LOG2E), (_Float16)(v1.y*LOG2E),
                      (_Float16)(v1.z*LOG2E), (_Float16)(v1.w*LOG2E) };
            *(hv8*)&sKV[9216 + row*72 + c8*8] = s;
        }
    }
    #pragma unroll
    for (int ii = 0; ii < 2; ++ii) {
        int u = tid + ii * 256;
        int row = u >> 3, c8 = u & 7;
        int sr = row < 63 ? row : 62;
        const float* src = relw + (size_t)sr * HD + c8*8;
        float4 v0 = *(const float4*)(src);
        float4 v1 = *(const float4*)(src + 4);
        hv8 s = { (_Float16)(v0.x*LOG2E), (_Float16)(v0.y*LOG2E),
                  (_Float16)(v0.z*LOG2E), (_Float16)(v0.w*LOG2E),
                  (_Float16)(v1.x*LOG2E), (_Float16)(v1.y*LOG2E),
                  (_Float16)(v1.z*LOG2E), (_Float16)(v1.w*LOG2E) };
        *(hv8*)&sKV[13824 + row*72 + c8*8] = s;
    }
    loadKV(0);
    __syncthreads();

    hv8 aQ0[2], aQ1[2];
    #pragma unroll
    for (int g = 0; g < 2; ++g) {
        int qrow = wave*32 + g*16 + l16;
        aQ0[g] = *(const hv8*)&sKV[qrow*72 + quad*8];
        aQ1[g] = *(const hv8*)&sKV[qrow*72 + 32 + quad*8];
    }
    __syncthreads();

    #pragma unroll
    for (int g = 0; g < 2; ++g)
        #pragma unroll
        for (int t = 0; t < 2; ++t) {
            int wr = wave + 31 - (t*16 + l16);
            hv8 b0 = *(const hv8*)&sKV[9216 + wr*72 + quad*8];
            hv8 b1 = *(const hv8*)&sKV[9216 + wr*72 + 32 + quad*8];
            f32x4 c = {0.f,0.f,0.f,0.f};
            c = __builtin_amdgcn_mfma_f32_16x16x32_f16(aQ0[g], b0, c, 0, 0, 0);
            c = __builtin_amdgcn_mfma_f32_16x16x32_f16(aQ1[g], b1, c, 0, 0, 0);
            #pragma unroll
            for (int r = 0; r < 4; ++r)
                sH[wave*32 + g*16 + quad*4 + r][t*16 + l16] = (_Float16)c[r];
        }
    #pragma unroll
    for (int g = 0; g < 2; ++g)
        #pragma unroll
        for (int t = 0; t < 4; ++t) {
            hv8 b0 = *(const hv8*)&sKV[13824 + (t*16 + l16)*72 + quad*8];
            hv8 b1 = *(const hv8*)&sKV[13824 + (t*16 + l16)*72 + 32 + quad*8];
            f32x4 c = {0.f,0.f,0.f,0.f};
            c = __builtin_amdgcn_mfma_f32_16x16x32_f16(aQ0[g], b0, c, 0, 0, 0);
            c = __builtin_amdgcn_mfma_f32_16x16x32_f16(aQ1[g], b1, c, 0, 0, 0);
            #pragma unroll
            for (int r = 0; r < 4; ++r)
                sKV[wave*2304 + (g*16 + quad*4 + r)*72 + t*16 + l16] = (_Float16)c[r];
        }
    float rwSw[2][2][4];
    #pragma unroll
    for (int g = 0; g < 2; ++g)
        #pragma unroll
        for (int j = 0; j < 2; ++j)
            #pragma unroll
            for (int r = 0; r < 4; ++r) {
                int q32 = g*16 + l16;
                int w   = q32 - j*16 - quad*4 - r + 31;   // 0..62
                rwSw[g][j][r] = (float)sKV[wave*2304 + q32*72 + w];
            }
    __syncthreads();
    writeKV(0);
    loadKV(1);
    __syncthreads();

    f32x4 o[2][4];
    #pragma unroll
    for (int g = 0; g < 2; ++g)
        #pragma unroll
        for (int n = 0; n < 4; ++n) o[g][n] = (f32x4){0.f,0.f,0.f,0.f};
    f32x4 lacc[2] = { (f32x4){0.f,0.f,0.f,0.f}, (f32x4){0.f,0.f,0.f,0.f} };
    const hv8 vone = { (_Float16)1.f, (_Float16)1.f, (_Float16)1.f, (_Float16)1.f,
                       (_Float16)1.f, (_Float16)1.f, (_Float16)1.f, (_Float16)1.f };

    for (int kt = 0; kt < 16; ++kt) {
        const int buf = kt & 1;
        if (kt < 15) writeKV(buf ^ 1);
        if (kt < 14) loadKV(kt + 2);

        float rhq[2][2];
        #pragma unroll
        for (int g = 0; g < 2; ++g) {
            unsigned pr = *(const unsigned*)&sH[wave*32 + g*16 + l16][kt*2];
            rhq[g][0] = (float)(*(const _Float16*)&pr);
            rhq[g][1] = (float)(*((const _Float16*)&pr + 1));
        }

        unsigned wpk[2][4][2];
        #pragma unroll
        for (int bb = 0; bb < 4; ++bb) {
            hv8 bK0 = *(const hv8*)&sKV[KOFFB(buf) + (bb*16 + l16)*72 + quad*8];
            hv8 bK1 = *(const hv8*)&sKV[KOFFB(buf) + (bb*16 + l16)*72 + 32 + quad*8];
            #pragma unroll
            for (int g = 0; g < 2; ++g) {
                f32x4 c;
                #pragma unroll
                for (int r = 0; r < 4; ++r)
                    c[r] = rhq[g][bb>>1] + rwSw[g][bb&1][r];
                c = __builtin_amdgcn_mfma_f32_16x16x32_f16(bK0, aQ0[g], c, 0, 0, 0);
                c = __builtin_amdgcn_mfma_f32_16x16x32_f16(bK1, aQ1[g], c, 0, 0, 0);
                #pragma unroll
                for (int rr = 0; rr < 2; ++rr) {
                    union { _Float16 hh[2]; unsigned u; } pu;
                    pu.hh[0] = (_Float16)fast_exp2(c[2*rr]);
                    pu.hh[1] = (_Float16)fast_exp2(c[2*rr+1]);
                    wpk[g][bb][rr] = pu.u;
                }
            }
        }

        hv8 aP[2][2];
        #pragma unroll
        for (int g = 0; g < 2; ++g)
            #pragma unroll
            for (int kk = 0; kk < 2; ++kk) {
                union { unsigned u4[4]; hv8 v; } cv;
                #pragma unroll
                for (int rr = 0; rr < 2; ++rr) {
                    unsigned e = wpk[g][2*kk][rr];
                    unsigned oo = wpk[g][2*kk+1][rr];
                    asm("v_permlane32_swap_b32 %0, %1" : "+v"(e), "+v"(oo));
                    asm("v_permlane16_swap_b32 %0, %1" : "+v"(e), "+v"(oo));
                    cv.u4[rr]     = e;
                    cv.u4[2 + rr] = oo;
                }
                aP[g][kk] = cv.v;
            }

        __builtin_amdgcn_s_setprio(1);
        #pragma unroll
        for (int g = 0; g < 2; ++g) {
            lacc[g] = __builtin_amdgcn_mfma_f32_16x16x32_f16(aP[g][0], vone, lacc[g], 0, 0, 0);
            lacc[g] = __builtin_amdgcn_mfma_f32_16x16x32_f16(aP[g][1], vone, lacc[g], 0, 0, 0);
        }
        #pragma unroll
        for (int nn = 0; nn < 4; ++nn) {
            hv8 bV0 = *(const hv8*)&sKV[VOFFB(buf) + (nn*16 + l16)*72 + quad*8];
            hv8 bV1 = *(const hv8*)&sKV[VOFFB(buf) + (nn*16 + l16)*72 + 32 + quad*8];
            #pragma unroll
            for (int g = 0; g < 2; ++g) {
                o[g][nn] = __builtin_amdgcn_mfma_f32_16x16x32_f16(aP[g][0], bV0, o[g][nn], 0, 0, 0);
                o[g][nn] = __builtin_amdgcn_mfma_f32_16x16x32_f16(aP[g][1], bV1, o[g][nn], 0, 0, 0);
            }
        }
        __builtin_amdgcn_s_setprio(0);

        __syncthreads();
    }

    #pragma unroll
    for (int g = 0; g < 2; ++g) {
        float inv[4];
        #pragma unroll
        for (int r = 0; r < 4; ++r) inv[r] = 1.f / lacc[g][r];
        #pragma unroll
        for (int n = 0; n < 4; ++n)
            #pragma unroll
            for (int r = 0; r < 4; ++r) {
                int t = qt*128 + wave*32 + g*16 + quad*4 + r;
                size_t addr = ((size_t)b * TT + t) * CC + h*HD + n*16 + l16;
                O[addr] = (_Float16)(o[g][n][r] * inv[r]);
            }
    }
}

// ---------------------------------------------------------------------------
extern "C" void kernel_launch(void* const* d_in, const int* in_sizes, int n_in,
                              void* d_out, int out_size, void* d_ws, size_t ws_size,
                              hipStream_t stream) {
    const float* x   = (const float*)d_in[0];
    const float* ctx = (const float*)d_in[1];
    const float* Wq  = (const float*)d_in[2];
    const float* Wk  = (const float*)d_in[3];
    const float* Wv  = (const float*)d_in[4];
    const float* Wo  = (const float*)d_in[5];
    const float* bo  = (const float*)d_in[6];
    const float* rh  = (const float*)d_in[7];
    const float* rw  = (const float*)d_in[8];
    float* out = (float*)d_out;

    const size_t MN = (size_t)BB * TT * CC;   // 6291456
    const size_t WN = (size_t)CC * CC;        // 589824
    _Float16* p = (_Float16*)d_ws;
    _Float16* xh  = p; p += MN;
    _Float16* ch  = p; p += MN;
    _Float16* WqT = p; p += WN;
    _Float16* WkT = p; p += WN;
    _Float16* WvT = p; p += WN;
    _Float16* WoT = p; p += WN;
    _Float16* Qh  = p; p += MN;
    _Float16* Kh  = p; p += MN;
    _Float16* VtB = p; p += MN;
    _Float16* Oh  = p; p += MN;

    dim3 blk(256);

    prep_fused<<<dim3(6720), blk, 0, stream>>>(
        x, ctx, xh, ch, (int)MN, Wq, Wk, Wv, Wo, WqT, WkT, WvT, WoT);

    gemm_qkv3<<<dim3(1152), blk, 0, stream>>>(
        xh, ch, WqT, WkT, WvT, Qh, Kh, VtB);

    attn_mfma<<<dim3(BB*NH*(TT/128)), blk, 0, stream>>>(
        Qh, Kh, VtB, rh, rw, Oh);

    gemm_out_f16<<<dim3(768), blk, 0, stream>>>(
        Oh, WoT, bo, out);
}

// Round 11
// 227.128 us; speedup vs baseline: 1.3625x; 1.0501x over previous
//
#include <hip/hip_runtime.h>
#include <math.h>

#define BB 8
#define TT 1024
#define CC 768
#define NH 12
#define HD 64
#define LOG2E 1.44269504088896f

typedef __attribute__((ext_vector_type(8))) _Float16 hv8;   // 8 fp16 (4 VGPRs)
typedef __attribute__((ext_vector_type(8))) short  short8;  // raw 16B
typedef __attribute__((ext_vector_type(4))) float  f32x4;

static __device__ __forceinline__ float fast_exp2(float x) {
#if __has_builtin(__builtin_amdgcn_exp2f)
    return __builtin_amdgcn_exp2f(x);
#else
    return exp2f(x);
#endif
}

// Async global->LDS DMA, 16B per lane (global_load_lds_dwordx4).
static __device__ __forceinline__ void gload_lds16(
    const _Float16* __restrict__ g, _Float16* l)
{
    __builtin_amdgcn_global_load_lds(
        (const __attribute__((address_space(1))) void*)g,
        (__attribute__((address_space(3))) void*)l, 16, 0, 0);
}

// ---------------------------------------------------------------------------
// Fused prep -- fp32->fp16 convert of x/ctx (blocks 0..6143) AND the 4
// weight transposes (blocks 6144..6719).  Wk carries 0.125*log2e.
// ---------------------------------------------------------------------------
__global__ __launch_bounds__(256) void prep_fused(
    const float* __restrict__ x, const float* __restrict__ ctx,
    _Float16* __restrict__ xh, _Float16* __restrict__ ch, int n,
    const float* __restrict__ Wq, const float* __restrict__ Wk,
    const float* __restrict__ Wv, const float* __restrict__ Wo,
    _Float16* __restrict__ WqT, _Float16* __restrict__ WkT,
    _Float16* __restrict__ WvT, _Float16* __restrict__ WoT)
{
    __shared__ float tile[64][65];
    const int bid = blockIdx.x;

    if (bid < 6144) {
        const float* in = (bid >= 3072) ? ctx : x;
        _Float16* out   = (bid >= 3072) ? ch  : xh;
        int bb2 = (bid >= 3072) ? bid - 3072 : bid;
        int i = (bb2 * 256 + threadIdx.x) * 8;
        if (i < n) {
            float4 v0 = *(const float4*)(in + i);
            float4 v1 = *(const float4*)(in + i + 4);
            hv8 h = { (_Float16)v0.x, (_Float16)v0.y, (_Float16)v0.z, (_Float16)v0.w,
                      (_Float16)v1.x, (_Float16)v1.y, (_Float16)v1.z, (_Float16)v1.w };
            *(hv8*)(out + i) = h;
        }
        return;
    }

    const int t  = bid - 6144;            // 0..575
    const int z  = t / 144;
    const int rm = t - z * 144;
    const int by = rm / 12, bx = rm - by * 12;

    const float* W = (z == 0) ? Wq : (z == 1) ? Wk : (z == 2) ? Wv : Wo;
    _Float16*   WT = (z == 0) ? WqT : (z == 1) ? WkT : (z == 2) ? WvT : WoT;
    const float scale = (z == 1) ? 0.125f * LOG2E : 1.0f;

    const int tx = threadIdx.x & 15, ty = threadIdx.x >> 4;
    const int n0 = bx * 64, k0 = by * 64;

    #pragma unroll
    for (int ii = 0; ii < 4; ++ii) {
        int k = ty + ii * 16;
        float4 v = *(const float4*)(W + (size_t)(k0 + k) * CC + n0 + tx * 4);
        tile[k][tx*4+0] = v.x; tile[k][tx*4+1] = v.y;
        tile[k][tx*4+2] = v.z; tile[k][tx*4+3] = v.w;
    }
    __syncthreads();
    #pragma unroll
    for (int ii = 0; ii < 4; ++ii) {
        int nn = ty + ii * 16;
        _Float16* dst = WT + (size_t)(n0 + nn) * CC + k0 + tx * 4;
        dst[0] = (_Float16)(tile[tx*4+0][nn] * scale);
        dst[1] = (_Float16)(tile[tx*4+1][nn] * scale);
        dst[2] = (_Float16)(tile[tx*4+2][nn] * scale);
        dst[3] = (_Float16)(tile[tx*4+3][nn] * scale);
    }
}

// ---------------------------------------------------------------------------
// Fused QKV GEMM -- R11: exact revert to R8's proven decode (220.7us best).
// R10's "per-XCD by-range across all z" remap thrashed L2 (each XCD needed
// xh+ctx panels AND all 3 weight mats = 6.6MB > 4MB; FETCH 30->54MB,
// qkv3 55->68us).  R8's decode concentrates each XCD on mostly one z:
// one input + one weight matrix fits.
// ---------------------------------------------------------------------------
__global__ __launch_bounds__(256) void gemm_qkv3(
    const _Float16* __restrict__ xh, const _Float16* __restrict__ ch,
    const _Float16* __restrict__ WqT, const _Float16* __restrict__ WkT,
    const _Float16* __restrict__ WvT,
    _Float16* __restrict__ Qh, _Float16* __restrict__ Kh,
    _Float16* __restrict__ Vt)
{
    const int bid = blockIdx.x;
    const int lid = (bid & 7) * 144 + (bid >> 3);
    const int z   = lid / 384;
    const int rem = lid - z * 384;
    const int by  = rem / 6;
    const int bx  = rem - by * 6;

    const _Float16* A  = (z == 0) ? xh : ch;
    const _Float16* BT = (z == 0) ? WqT : (z == 1) ? WkT : WvT;

    __shared__ _Float16 smem[128 * 137];
    _Float16* sA = smem;
    _Float16* sB = smem + 128 * 64;

    const int tid  = threadIdx.x;
    const int wave = tid >> 6, lane = tid & 63;
    const int quad = lane >> 4, l16 = lane & 15;
    const int m0 = by * 128, n0 = bx * 128;
    const int mw = (wave & 1) * 64, nw = (wave >> 1) * 64;

    const int srow = wave * 32 + (lane >> 3);
    const int scol = (lane & 7) * 8;

    f32x4 acc[4][4];
    #pragma unroll
    for (int i = 0; i < 4; ++i)
        #pragma unroll
        for (int j = 0; j < 4; ++j) acc[i][j] = (f32x4){0.f,0.f,0.f,0.f};

    for (int kt = 0; kt < CC; kt += 64) {
        #pragma unroll
        for (int i = 0; i < 4; ++i) {
            gload_lds16(A  + (size_t)(m0 + srow + i*8) * CC + kt + scol,
                        &sA[(wave*32 + i*8) * 64]);
            gload_lds16(BT + (size_t)(n0 + srow + i*8) * CC + kt + scol,
                        &sB[(wave*32 + i*8) * 64]);
        }
        __syncthreads();
        #pragma unroll
        for (int kk = 0; kk < 2; ++kk) {
            hv8 af[4], bf[4];
            #pragma unroll
            for (int mi = 0; mi < 4; ++mi)
                af[mi] = *(const hv8*)&sA[(mw + mi*16 + l16)*64 + kk*32 + quad*8];
            #pragma unroll
            for (int nj = 0; nj < 4; ++nj)
                bf[nj] = *(const hv8*)&sB[(nw + nj*16 + l16)*64 + kk*32 + quad*8];
            #pragma unroll
            for (int mi = 0; mi < 4; ++mi)
                #pragma unroll
                for (int nj = 0; nj < 4; ++nj)
                    acc[mi][nj] = __builtin_amdgcn_mfma_f32_16x16x32_f16(
                        af[mi], bf[nj], acc[mi][nj], 0, 0, 0);
        }
        __syncthreads();
    }

    if (z < 2) {
        _Float16* Chead = (z == 0) ? Qh : Kh;
        _Float16* sT = smem;   // [128][137]
        #pragma unroll
        for (int mi = 0; mi < 4; ++mi)
            #pragma unroll
            for (int nj = 0; nj < 4; ++nj)
                #pragma unroll
                for (int r = 0; r < 4; ++r)
                    sT[(mw + mi*16 + quad*4 + r)*137 + nw + nj*16 + l16] =
                        (_Float16)acc[mi][nj][r];
        __syncthreads();
        #pragma unroll
        for (int ii = 0; ii < 8; ++ii) {
            int u = tid + ii * 256;
            int row = u >> 4;
            int chk = u & 15;
            hv8 o;
            #pragma unroll
            for (int j = 0; j < 8; ++j) o[j] = sT[row*137 + chk*8 + j];
            int gm = m0 + row, gn = n0 + chk*8;
            int bI = gm >> 10, tI = gm & 1023;
            int hI = gn >> 6,  dI = gn & 63;
            *(hv8*)(Chead + (((size_t)bI * NH + hI) * TT + tI) * HD + dI) = o;
        }
    } else {
        _Float16* sT = smem;   // [128][137]
        #pragma unroll
        for (int mi = 0; mi < 4; ++mi)
            #pragma unroll
            for (int nj = 0; nj < 4; ++nj)
                #pragma unroll
                for (int r = 0; r < 4; ++r)
                    sT[(mw + mi*16 + quad*4 + r)*137 + nw + nj*16 + l16] =
                        (_Float16)acc[mi][nj][r];
        __syncthreads();
        #pragma unroll
        for (int ii = 0; ii < 8; ++ii) {
            int u = tid + ii * 256;
            int dloc = u >> 4;
            int tch  = u & 15;
            hv8 o;
            #pragma unroll
            for (int j = 0; j < 8; ++j) o[j] = sT[(tch*8 + j)*137 + dloc];
            int gn = n0 + dloc;
            int hI = gn >> 6, dI = gn & 63;
            int gm = m0 + tch * 8;
            int bI = gm >> 10, tI = gm & 1023;
            *(hv8*)(Vt + (((size_t)bI * NH + hI) * HD + dI) * TT + tI) = o;
        }
    }
}

// ---------------------------------------------------------------------------
// fp16 single-pass output GEMM (unchanged from R5).
// ---------------------------------------------------------------------------
__global__ __launch_bounds__(256) void gemm_out_f16(
    const _Float16* __restrict__ A, const _Float16* __restrict__ BT,
    const float* __restrict__ bias, float* __restrict__ out)
{
    __shared__ _Float16 sA[128 * 64];
    __shared__ _Float16 sB[64 * 64];

    const int bid = blockIdx.x;
    const int lid = (bid & 7) * 96 + (bid >> 3);
    const int by  = lid / 12;
    const int bx  = lid - by * 12;

    const int tid  = threadIdx.x;
    const int wave = tid >> 6, lane = tid & 63;
    const int quad = lane >> 4, l16 = lane & 15;
    const int m0 = by * 128, n0 = bx * 64;
    const int mw = (wave & 1) * 64, nw = (wave >> 1) * 32;

    const int srow = lane >> 3;
    const int scol = (lane & 7) * 8;

    f32x4 acc[4][2];
    #pragma unroll
    for (int i = 0; i < 4; ++i)
        #pragma unroll
        for (int j = 0; j < 2; ++j) acc[i][j] = (f32x4){0.f,0.f,0.f,0.f};

    for (int kt = 0; kt < CC; kt += 64) {
        #pragma unroll
        for (int i = 0; i < 4; ++i)
            gload_lds16(A + (size_t)(m0 + wave*32 + i*8 + srow) * CC + kt + scol,
                        &sA[(wave*32 + i*8) * 64]);
        #pragma unroll
        for (int i = 0; i < 2; ++i)
            gload_lds16(BT + (size_t)(n0 + wave*16 + i*8 + srow) * CC + kt + scol,
                        &sB[(wave*16 + i*8) * 64]);
        __syncthreads();
        #pragma unroll
        for (int kk = 0; kk < 2; ++kk) {
            hv8 af[4], bf[2];
            #pragma unroll
            for (int mi = 0; mi < 4; ++mi)
                af[mi] = *(const hv8*)&sA[(mw + mi*16 + l16)*64 + kk*32 + quad*8];
            #pragma unroll
            for (int nj = 0; nj < 2; ++nj)
                bf[nj] = *(const hv8*)&sB[(nw + nj*16 + l16)*64 + kk*32 + quad*8];
            #pragma unroll
            for (int mi = 0; mi < 4; ++mi)
                #pragma unroll
                for (int nj = 0; nj < 2; ++nj)
                    acc[mi][nj] = __builtin_amdgcn_mfma_f32_16x16x32_f16(
                        af[mi], bf[nj], acc[mi][nj], 0, 0, 0);
        }
        __syncthreads();
    }

    #pragma unroll
    for (int mi = 0; mi < 4; ++mi)
        #pragma unroll
        for (int nj = 0; nj < 2; ++nj)
            #pragma unroll
            for (int r = 0; r < 4; ++r) {
                int gm = m0 + mw + mi*16 + quad*4 + r;
                int gn = n0 + nw + nj*16 + l16;
                out[(size_t)gm * CC + gn] = acc[mi][nj][r] + bias[gn];
            }
}

// ---------------------------------------------------------------------------
// fp16 MFMA flash attention (unchanged from R8: swapped QK^T, register-P via
// permlane repack, K/V double-buffer, 1 barrier/kt, XCD swizzle).
// ---------------------------------------------------------------------------
#define KOFFB(b) ((b)*9216)          // K tile of buf b (halves)
#define VOFFB(b) ((b)*9216 + 4608)   // V tile of buf b

__global__ __launch_bounds__(256) void attn_mfma(
    const _Float16* __restrict__ Q, const _Float16* __restrict__ K,
    const _Float16* __restrict__ Vt, const float* __restrict__ relh,
    const float* __restrict__ relw, _Float16* __restrict__ O)
{
    __shared__ _Float16 sKV[18432];     // 2 dbuf x {K[64][72], V[64][72]}
    __shared__ _Float16 sH [128][34];   // rh table [qi][hk]

    const int tid  = threadIdx.x;
    const int wave = tid >> 6, lane = tid & 63;
    const int quad = lane >> 4, l16 = lane & 15;

    const int bid = blockIdx.x;
    const int idx = bid >> 3;
    const int qt  = idx & 7;
    const int bh  = (bid & 7) + 8 * (idx >> 3);
    const int h   = bh % NH;
    const int b   = bh / NH;
    const size_t hbase = ((size_t)b * NH + h) * TT * HD;

    short8 pK[2], pV[2];
    auto loadKV = [&](int kt) {
        #pragma unroll
        for (int ii = 0; ii < 2; ++ii) {
            int u = tid + ii * 256;
            int row = u >> 3, c8 = u & 7;
            pK[ii] = *(const short8*)(K  + hbase + (size_t)(kt*64 + row) * HD + c8*8);
            pV[ii] = *(const short8*)(Vt + hbase + (size_t)row * TT + kt*64 + c8*8);
        }
    };
    auto writeKV = [&](int bf) {
        #pragma unroll
        for (int ii = 0; ii < 2; ++ii) {
            int u = tid + ii * 256;
            int row = u >> 3, c8 = u & 7;
            *(short8*)&sKV[KOFFB(bf) + row*72 + c8*8] = pK[ii];
            *(short8*)&sKV[VOFFB(bf) + row*72 + c8*8] = pV[ii];
        }
    };

    #pragma unroll
    for (int ii = 0; ii < 4; ++ii) {
        int u = tid + ii * 256;
        int row = u >> 3, c8 = u & 7;
        *(short8*)&sKV[row*72 + c8*8] =
            *(const short8*)(Q + hbase + (size_t)(qt*128 + row) * HD + c8*8);
    }
    #pragma unroll
    for (int ii = 0; ii < 2; ++ii) {
        int u = tid + ii * 256;
        if (u < 280) {                 // 35 rows x 8 chunks of relh window
            int row = u >> 3, c8 = u & 7;
            const float* src = relh + (size_t)(4*qt + row) * HD + c8*8;
            float4 v0 = *(const float4*)(src);
            float4 v1 = *(const float4*)(src + 4);
            hv8 s = { (_Float16)(v0.x*LOG2E), (_Float16)(v0.y*LOG2E),
                      (_Float16)(v0.z*LOG2E), (_Float16)(v0.w*LOG2E),
                      (_Float16)(v1.x*LOG2E), (_Float16)(v1.y*LOG2E),
                      (_Float16)(v1.z*LOG2E), (_Float16)(v1.w*LOG2E) };
            *(hv8*)&sKV[9216 + row*72 + c8*8] = s;
        }
    }
    #pragma unroll
    for (int ii = 0; ii < 2; ++ii) {
        int u = tid + ii * 256;
        int row = u >> 3, c8 = u & 7;
        int sr = row < 63 ? row : 62;
        const float* src = relw + (size_t)sr * HD + c8*8;
        float4 v0 = *(const float4*)(src);
        float4 v1 = *(const float4*)(src + 4);
        hv8 s = { (_Float16)(v0.x*LOG2E), (_Float16)(v0.y*LOG2E),
                  (_Float16)(v0.z*LOG2E), (_Float16)(v0.w*LOG2E),
                  (_Float16)(v1.x*LOG2E), (_Float16)(v1.y*LOG2E),
                  (_Float16)(v1.z*LOG2E), (_Float16)(v1.w*LOG2E) };
        *(hv8*)&sKV[13824 + row*72 + c8*8] = s;
    }
    loadKV(0);
    __syncthreads();

    hv8 aQ0[2], aQ1[2];
    #pragma unroll
    for (int g = 0; g < 2; ++g) {
        int qrow = wave*32 + g*16 + l16;
        aQ0[g] = *(const hv8*)&sKV[qrow*72 + quad*8];
        aQ1[g] = *(const hv8*)&sKV[qrow*72 + 32 + quad*8];
    }
    __syncthreads();

    #pragma unroll
    for (int g = 0; g < 2; ++g)
        #pragma unroll
        for (int t = 0; t < 2; ++t) {
            int wr = wave + 31 - (t*16 + l16);
            hv8 b0 = *(const hv8*)&sKV[9216 + wr*72 + quad*8];
            hv8 b1 = *(const hv8*)&sKV[9216 + wr*72 + 32 + quad*8];
            f32x4 c = {0.f,0.f,0.f,0.f};
            c = __builtin_amdgcn_mfma_f32_16x16x32_f16(aQ0[g], b0, c, 0, 0, 0);
            c = __builtin_amdgcn_mfma_f32_16x16x32_f16(aQ1[g], b1, c, 0, 0, 0);
            #pragma unroll
            for (int r = 0; r < 4; ++r)
                sH[wave*32 + g*16 + quad*4 + r][t*16 + l16] = (_Float16)c[r];
        }
    #pragma unroll
    for (int g = 0; g < 2; ++g)
        #pragma unroll
        for (int t = 0; t < 4; ++t) {
            hv8 b0 = *(const hv8*)&sKV[13824 + (t*16 + l16)*72 + quad*8];
            hv8 b1 = *(const hv8*)&sKV[13824 + (t*16 + l16)*72 + 32 + quad*8];
            f32x4 c = {0.f,0.f,0.f,0.f};
            c = __builtin_amdgcn_mfma_f32_16x16x32_f16(aQ0[g], b0, c, 0, 0, 0);
            c = __builtin_amdgcn_mfma_f32_16x16x32_f16(aQ1[g], b1, c, 0, 0, 0);
            #pragma unroll
            for (int r = 0; r < 4; ++r)
                sKV[wave*2304 + (g*16 + quad*4 + r)*72 + t*16 + l16] = (_Float16)c[r];
        }
    float rwSw[2][2][4];
    #pragma unroll
    for (int g = 0; g < 2; ++g)
        #pragma unroll
        for (int j = 0; j < 2; ++j)
            #pragma unroll
            for (int r = 0; r < 4; ++r) {
                int q32 = g*16 + l16;
                int w   = q32 - j*16 - quad*4 - r + 31;   // 0..62
                rwSw[g][j][r] = (float)sKV[wave*2304 + q32*72 + w];
            }
    __syncthreads();
    writeKV(0);
    loadKV(1);
    __syncthreads();

    f32x4 o[2][4];
    #pragma unroll
    for (int g = 0; g < 2; ++g)
        #pragma unroll
        for (int n = 0; n < 4; ++n) o[g][n] = (f32x4){0.f,0.f,0.f,0.f};
    f32x4 lacc[2] = { (f32x4){0.f,0.f,0.f,0.f}, (f32x4){0.f,0.f,0.f,0.f} };
    const hv8 vone = { (_Float16)1.f, (_Float16)1.f, (_Float16)1.f, (_Float16)1.f,
                       (_Float16)1.f, (_Float16)1.f, (_Float16)1.f, (_Float16)1.f };

    for (int kt = 0; kt < 16; ++kt) {
        const int buf = kt & 1;
        if (kt < 15) writeKV(buf ^ 1);
        if (kt < 14) loadKV(kt + 2);

        float rhq[2][2];
        #pragma unroll
        for (int g = 0; g < 2; ++g) {
            unsigned pr = *(const unsigned*)&sH[wave*32 + g*16 + l16][kt*2];
            rhq[g][0] = (float)(*(const _Float16*)&pr);
            rhq[g][1] = (float)(*((const _Float16*)&pr + 1));
        }

        unsigned wpk[2][4][2];
        #pragma unroll
        for (int bb = 0; bb < 4; ++bb) {
            hv8 bK0 = *(const hv8*)&sKV[KOFFB(buf) + (bb*16 + l16)*72 + quad*8];
            hv8 bK1 = *(const hv8*)&sKV[KOFFB(buf) + (bb*16 + l16)*72 + 32 + quad*8];
            #pragma unroll
            for (int g = 0; g < 2; ++g) {
                f32x4 c;
                #pragma unroll
                for (int r = 0; r < 4; ++r)
                    c[r] = rhq[g][bb>>1] + rwSw[g][bb&1][r];
                c = __builtin_amdgcn_mfma_f32_16x16x32_f16(bK0, aQ0[g], c, 0, 0, 0);
                c = __builtin_amdgcn_mfma_f32_16x16x32_f16(bK1, aQ1[g], c, 0, 0, 0);
                #pragma unroll
                for (int rr = 0; rr < 2; ++rr) {
                    union { _Float16 hh[2]; unsigned u; } pu;
                    pu.hh[0] = (_Float16)fast_exp2(c[2*rr]);
                    pu.hh[1] = (_Float16)fast_exp2(c[2*rr+1]);
                    wpk[g][bb][rr] = pu.u;
                }
            }
        }

        hv8 aP[2][2];
        #pragma unroll
        for (int g = 0; g < 2; ++g)
            #pragma unroll
            for (int kk = 0; kk < 2; ++kk) {
                union { unsigned u4[4]; hv8 v; } cv;
                #pragma unroll
                for (int rr = 0; rr < 2; ++rr) {
                    unsigned e = wpk[g][2*kk][rr];
                    unsigned oo = wpk[g][2*kk+1][rr];
                    asm("v_permlane32_swap_b32 %0, %1" : "+v"(e), "+v"(oo));
                    asm("v_permlane16_swap_b32 %0, %1" : "+v"(e), "+v"(oo));
                    cv.u4[rr]     = e;
                    cv.u4[2 + rr] = oo;
                }
                aP[g][kk] = cv.v;
            }

        __builtin_amdgcn_s_setprio(1);
        #pragma unroll
        for (int g = 0; g < 2; ++g) {
            lacc[g] = __builtin_amdgcn_mfma_f32_16x16x32_f16(aP[g][0], vone, lacc[g], 0, 0, 0);
            lacc[g] = __builtin_amdgcn_mfma_f32_16x16x32_f16(aP[g][1], vone, lacc[g], 0, 0, 0);
        }
        #pragma unroll
        for (int nn = 0; nn < 4; ++nn) {
            hv8 bV0 = *(const hv8*)&sKV[VOFFB(buf) + (nn*16 + l16)*72 + quad*8];
            hv8 bV1 = *(const hv8*)&sKV[VOFFB(buf) + (nn*16 + l16)*72 + 32 + quad*8];
            #pragma unroll
            for (int g = 0; g < 2; ++g) {
                o[g][nn] = __builtin_amdgcn_mfma_f32_16x16x32_f16(aP[g][0], bV0, o[g][nn], 0, 0, 0);
                o[g][nn] = __builtin_amdgcn_mfma_f32_16x16x32_f16(aP[g][1], bV1, o[g][nn], 0, 0, 0);
            }
        }
        __builtin_amdgcn_s_setprio(0);

        __syncthreads();
    }

    #pragma unroll
    for (int g = 0; g < 2; ++g) {
        float inv[4];
        #pragma unroll
        for (int r = 0; r < 4; ++r) inv[r] = 1.f / lacc[g][r];
        #pragma unroll
        for (int n = 0; n < 4; ++n)
            #pragma unroll
            for (int r = 0; r < 4; ++r) {
                int t = qt*128 + wave*32 + g*16 + quad*4 + r;
                size_t addr = ((size_t)b * TT + t) * CC + h*HD + n*16 + l16;
                O[addr] = (_Float16)(o[g][n][r] * inv[r]);
            }
    }
}

// ---------------------------------------------------------------------------
extern "C" void kernel_launch(void* const* d_in, const int* in_sizes, int n_in,
                              void* d_out, int out_size, void* d_ws, size_t ws_size,
                              hipStream_t stream) {
    const float* x   = (const float*)d_in[0];
    const float* ctx = (const float*)d_in[1];
    const float* Wq  = (const float*)d_in[2];
    const float* Wk  = (const float*)d_in[3];
    const float* Wv  = (const float*)d_in[4];
    const float* Wo  = (const float*)d_in[5];
    const float* bo  = (const float*)d_in[6];
    const float* rh  = (const float*)d_in[7];
    const float* rw  = (const float*)d_in[8];
    float* out = (float*)d_out;

    const size_t MN = (size_t)BB * TT * CC;   // 6291456
    const size_t WN = (size_t)CC * CC;        // 589824
    _Float16* p = (_Float16*)d_ws;
    _Float16* xh  = p; p += MN;
    _Float16* ch  = p; p += MN;
    _Float16* WqT = p; p += WN;
    _Float16* WkT = p; p += WN;
    _Float16* WvT = p; p += WN;
    _Float16* WoT = p; p += WN;
    _Float16* Qh  = p; p += MN;
    _Float16* Kh  = p; p += MN;
    _Float16* VtB = p; p += MN;
    _Float16* Oh  = p; p += MN;

    dim3 blk(256);

    prep_fused<<<dim3(6720), blk, 0, stream>>>(
        x, ctx, xh, ch, (int)MN, Wq, Wk, Wv, Wo, WqT, WkT, WvT, WoT);

    gemm_qkv3<<<dim3(1152), blk, 0, stream>>>(
        xh, ch, WqT, WkT, WvT, Qh, Kh, VtB);

    attn_mfma<<<dim3(BB*NH*(TT/128)), blk, 0, stream>>>(
        Qh, Kh, VtB, rh, rw, Oh);

    gemm_out_f16<<<dim3(768), blk, 0, stream>>>(
        Oh, WoT, bo, out);
}

// Round 13
// 220.832 us; speedup vs baseline: 1.4013x; 1.0285x over previous
//
#include <hip/hip_runtime.h>
#include <math.h>

#define BB 8
#define TT 1024
#define CC 768
#define NH 12
#define HD 64
#define LOG2E 1.44269504088896f

typedef __attribute__((ext_vector_type(8))) _Float16 hv8;   // 8 fp16 (4 VGPRs)
typedef __attribute__((ext_vector_type(8))) short  short8;  // raw 16B
typedef __attribute__((ext_vector_type(4))) float  f32x4;

static __device__ __forceinline__ float fast_exp2(float x) {
#if __has_builtin(__builtin_amdgcn_exp2f)
    return __builtin_amdgcn_exp2f(x);
#else
    return exp2f(x);
#endif
}

// Async global->LDS DMA, 16B per lane (global_load_lds_dwordx4).
static __device__ __forceinline__ void gload_lds16(
    const _Float16* __restrict__ g, _Float16* l)
{
    __builtin_amdgcn_global_load_lds(
        (const __attribute__((address_space(1))) void*)g,
        (__attribute__((address_space(3))) void*)l, 16, 0, 0);
}

// ---------------------------------------------------------------------------
// Fused prep -- fp32->fp16 convert of x/ctx (blocks 0..6143) AND the 4
// weight transposes (blocks 6144..6719).  Wk carries 0.125*log2e (exp2
// domain for attn).
// ---------------------------------------------------------------------------
__global__ __launch_bounds__(256) void prep_fused(
    const float* __restrict__ x, const float* __restrict__ ctx,
    _Float16* __restrict__ xh, _Float16* __restrict__ ch, int n,
    const float* __restrict__ Wq, const float* __restrict__ Wk,
    const float* __restrict__ Wv, const float* __restrict__ Wo,
    _Float16* __restrict__ WqT, _Float16* __restrict__ WkT,
    _Float16* __restrict__ WvT, _Float16* __restrict__ WoT)
{
    __shared__ float tile[64][65];
    const int bid = blockIdx.x;

    if (bid < 6144) {
        const float* in = (bid >= 3072) ? ctx : x;
        _Float16* out   = (bid >= 3072) ? ch  : xh;
        int bb2 = (bid >= 3072) ? bid - 3072 : bid;
        int i = (bb2 * 256 + threadIdx.x) * 8;
        if (i < n) {
            float4 v0 = *(const float4*)(in + i);
            float4 v1 = *(const float4*)(in + i + 4);
            hv8 h = { (_Float16)v0.x, (_Float16)v0.y, (_Float16)v0.z, (_Float16)v0.w,
                      (_Float16)v1.x, (_Float16)v1.y, (_Float16)v1.z, (_Float16)v1.w };
            *(hv8*)(out + i) = h;
        }
        return;
    }

    const int t  = bid - 6144;            // 0..575
    const int z  = t / 144;
    const int rm = t - z * 144;
    const int by = rm / 12, bx = rm - by * 12;

    const float* W = (z == 0) ? Wq : (z == 1) ? Wk : (z == 2) ? Wv : Wo;
    _Float16*   WT = (z == 0) ? WqT : (z == 1) ? WkT : (z == 2) ? WvT : WoT;
    const float scale = (z == 1) ? 0.125f * LOG2E : 1.0f;

    const int tx = threadIdx.x & 15, ty = threadIdx.x >> 4;
    const int n0 = bx * 64, k0 = by * 64;

    #pragma unroll
    for (int ii = 0; ii < 4; ++ii) {
        int k = ty + ii * 16;
        float4 v = *(const float4*)(W + (size_t)(k0 + k) * CC + n0 + tx * 4);
        tile[k][tx*4+0] = v.x; tile[k][tx*4+1] = v.y;
        tile[k][tx*4+2] = v.z; tile[k][tx*4+3] = v.w;
    }
    __syncthreads();
    #pragma unroll
    for (int ii = 0; ii < 4; ++ii) {
        int nn = ty + ii * 16;
        _Float16* dst = WT + (size_t)(n0 + nn) * CC + k0 + tx * 4;
        dst[0] = (_Float16)(tile[tx*4+0][nn] * scale);
        dst[1] = (_Float16)(tile[tx*4+1][nn] * scale);
        dst[2] = (_Float16)(tile[tx*4+2][nn] * scale);
        dst[3] = (_Float16)(tile[tx*4+3][nn] * scale);
    }
}

// ---------------------------------------------------------------------------
// Fused QKV GEMM (verified R8 config: global_load_lds staging into linear
// [128][64] LDS, 2-barrier K-loop, R8 XCD decode -- each XCD concentrates
// on mostly one z, so one input + one weight matrix fits its 4MB L2.
// R10's by-range remap thrashed L2: 6.6MB/XCD working set, FETCH 30->54MB).
// ---------------------------------------------------------------------------
__global__ __launch_bounds__(256) void gemm_qkv3(
    const _Float16* __restrict__ xh, const _Float16* __restrict__ ch,
    const _Float16* __restrict__ WqT, const _Float16* __restrict__ WkT,
    const _Float16* __restrict__ WvT,
    _Float16* __restrict__ Qh, _Float16* __restrict__ Kh,
    _Float16* __restrict__ Vt)
{
    const int bid = blockIdx.x;
    const int lid = (bid & 7) * 144 + (bid >> 3);
    const int z   = lid / 384;
    const int rem = lid - z * 384;
    const int by  = rem / 6;
    const int bx  = rem - by * 6;

    const _Float16* A  = (z == 0) ? xh : ch;
    const _Float16* BT = (z == 0) ? WqT : (z == 1) ? WkT : WvT;

    __shared__ _Float16 smem[128 * 137];
    _Float16* sA = smem;
    _Float16* sB = smem + 128 * 64;

    const int tid  = threadIdx.x;
    const int wave = tid >> 6, lane = tid & 63;
    const int quad = lane >> 4, l16 = lane & 15;
    const int m0 = by * 128, n0 = bx * 128;
    const int mw = (wave & 1) * 64, nw = (wave >> 1) * 64;

    const int srow = wave * 32 + (lane >> 3);
    const int scol = (lane & 7) * 8;

    f32x4 acc[4][4];
    #pragma unroll
    for (int i = 0; i < 4; ++i)
        #pragma unroll
        for (int j = 0; j < 4; ++j) acc[i][j] = (f32x4){0.f,0.f,0.f,0.f};

    for (int kt = 0; kt < CC; kt += 64) {
        #pragma unroll
        for (int i = 0; i < 4; ++i) {
            gload_lds16(A  + (size_t)(m0 + srow + i*8) * CC + kt + scol,
                        &sA[(wave*32 + i*8) * 64]);
            gload_lds16(BT + (size_t)(n0 + srow + i*8) * CC + kt + scol,
                        &sB[(wave*32 + i*8) * 64]);
        }
        __syncthreads();
        #pragma unroll
        for (int kk = 0; kk < 2; ++kk) {
            hv8 af[4], bf[4];
            #pragma unroll
            for (int mi = 0; mi < 4; ++mi)
                af[mi] = *(const hv8*)&sA[(mw + mi*16 + l16)*64 + kk*32 + quad*8];
            #pragma unroll
            for (int nj = 0; nj < 4; ++nj)
                bf[nj] = *(const hv8*)&sB[(nw + nj*16 + l16)*64 + kk*32 + quad*8];
            #pragma unroll
            for (int mi = 0; mi < 4; ++mi)
                #pragma unroll
                for (int nj = 0; nj < 4; ++nj)
                    acc[mi][nj] = __builtin_amdgcn_mfma_f32_16x16x32_f16(
                        af[mi], bf[nj], acc[mi][nj], 0, 0, 0);
        }
        __syncthreads();
    }

    if (z < 2) {
        _Float16* Chead = (z == 0) ? Qh : Kh;
        _Float16* sT = smem;   // [128][137]
        #pragma unroll
        for (int mi = 0; mi < 4; ++mi)
            #pragma unroll
            for (int nj = 0; nj < 4; ++nj)
                #pragma unroll
                for (int r = 0; r < 4; ++r)
                    sT[(mw + mi*16 + quad*4 + r)*137 + nw + nj*16 + l16] =
                        (_Float16)acc[mi][nj][r];
        __syncthreads();
        #pragma unroll
        for (int ii = 0; ii < 8; ++ii) {
            int u = tid + ii * 256;
            int row = u >> 4;
            int chk = u & 15;
            hv8 o;
            #pragma unroll
            for (int j = 0; j < 8; ++j) o[j] = sT[row*137 + chk*8 + j];
            int gm = m0 + row, gn = n0 + chk*8;
            int bI = gm >> 10, tI = gm & 1023;
            int hI = gn >> 6,  dI = gn & 63;
            *(hv8*)(Chead + (((size_t)bI * NH + hI) * TT + tI) * HD + dI) = o;
        }
    } else {
        _Float16* sT = smem;   // [128][137]
        #pragma unroll
        for (int mi = 0; mi < 4; ++mi)
            #pragma unroll
            for (int nj = 0; nj < 4; ++nj)
                #pragma unroll
                for (int r = 0; r < 4; ++r)
                    sT[(mw + mi*16 + quad*4 + r)*137 + nw + nj*16 + l16] =
                        (_Float16)acc[mi][nj][r];
        __syncthreads();
        #pragma unroll
        for (int ii = 0; ii < 8; ++ii) {
            int u = tid + ii * 256;
            int dloc = u >> 4;
            int tch  = u & 15;
            hv8 o;
            #pragma unroll
            for (int j = 0; j < 8; ++j) o[j] = sT[(tch*8 + j)*137 + dloc];
            int gn = n0 + dloc;
            int hI = gn >> 6, dI = gn & 63;
            int gm = m0 + tch * 8;
            int bI = gm >> 10, tI = gm & 1023;
            *(hv8*)(Vt + (((size_t)bI * NH + hI) * HD + dI) * TT + tI) = o;
        }
    }
}

// ---------------------------------------------------------------------------
// fp16 single-pass output GEMM (verified: 128x64 tile, 768 blocks = 3/CU,
// bijective XCD swizzle, global_load_lds staging).
// ---------------------------------------------------------------------------
__global__ __launch_bounds__(256) void gemm_out_f16(
    const _Float16* __restrict__ A, const _Float16* __restrict__ BT,
    const float* __restrict__ bias, float* __restrict__ out)
{
    __shared__ _Float16 sA[128 * 64];
    __shared__ _Float16 sB[64 * 64];

    const int bid = blockIdx.x;
    const int lid = (bid & 7) * 96 + (bid >> 3);
    const int by  = lid / 12;
    const int bx  = lid - by * 12;

    const int tid  = threadIdx.x;
    const int wave = tid >> 6, lane = tid & 63;
    const int quad = lane >> 4, l16 = lane & 15;
    const int m0 = by * 128, n0 = bx * 64;
    const int mw = (wave & 1) * 64, nw = (wave >> 1) * 32;

    const int srow = lane >> 3;
    const int scol = (lane & 7) * 8;

    f32x4 acc[4][2];
    #pragma unroll
    for (int i = 0; i < 4; ++i)
        #pragma unroll
        for (int j = 0; j < 2; ++j) acc[i][j] = (f32x4){0.f,0.f,0.f,0.f};

    for (int kt = 0; kt < CC; kt += 64) {
        #pragma unroll
        for (int i = 0; i < 4; ++i)
            gload_lds16(A + (size_t)(m0 + wave*32 + i*8 + srow) * CC + kt + scol,
                        &sA[(wave*32 + i*8) * 64]);
        #pragma unroll
        for (int i = 0; i < 2; ++i)
            gload_lds16(BT + (size_t)(n0 + wave*16 + i*8 + srow) * CC + kt + scol,
                        &sB[(wave*16 + i*8) * 64]);
        __syncthreads();
        #pragma unroll
        for (int kk = 0; kk < 2; ++kk) {
            hv8 af[4], bf[2];
            #pragma unroll
            for (int mi = 0; mi < 4; ++mi)
                af[mi] = *(const hv8*)&sA[(mw + mi*16 + l16)*64 + kk*32 + quad*8];
            #pragma unroll
            for (int nj = 0; nj < 2; ++nj)
                bf[nj] = *(const hv8*)&sB[(nw + nj*16 + l16)*64 + kk*32 + quad*8];
            #pragma unroll
            for (int mi = 0; mi < 4; ++mi)
                #pragma unroll
                for (int nj = 0; nj < 2; ++nj)
                    acc[mi][nj] = __builtin_amdgcn_mfma_f32_16x16x32_f16(
                        af[mi], bf[nj], acc[mi][nj], 0, 0, 0);
        }
        __syncthreads();
    }

    #pragma unroll
    for (int mi = 0; mi < 4; ++mi)
        #pragma unroll
        for (int nj = 0; nj < 2; ++nj)
            #pragma unroll
            for (int r = 0; r < 4; ++r) {
                int gm = m0 + mw + mi*16 + quad*4 + r;
                int gn = n0 + nw + nj*16 + l16;
                out[(size_t)gm * CC + gn] = acc[mi][nj][r] + bias[gn];
            }
}

// ---------------------------------------------------------------------------
// fp16 MFMA flash attention (verified R8 kernel, session best 55.3us):
// swapped QK^T -> register-resident P via permlane32/16 repack consumed at
// K=32 MFMA rate; K/V double-buffer, 1 barrier/kt; exp2-domain biases via
// MFMA C-init; MFMA row-sum; T14 2-deep prefetch; XCD-local K/V swizzle.
// (R12's 8-wave occupancy variant produced NaN -- reverted.)
// ---------------------------------------------------------------------------
#define KOFFB(b) ((b)*9216)          // K tile of buf b (halves)
#define VOFFB(b) ((b)*9216 + 4608)   // V tile of buf b

__global__ __launch_bounds__(256) void attn_mfma(
    const _Float16* __restrict__ Q, const _Float16* __restrict__ K,
    const _Float16* __restrict__ Vt, const float* __restrict__ relh,
    const float* __restrict__ relw, _Float16* __restrict__ O)
{
    __shared__ _Float16 sKV[18432];     // 2 dbuf x {K[64][72], V[64][72]}
    __shared__ _Float16 sH [128][34];   // rh table [qi][hk]

    const int tid  = threadIdx.x;
    const int wave = tid >> 6, lane = tid & 63;
    const int quad = lane >> 4, l16 = lane & 15;

    const int bid = blockIdx.x;
    const int idx = bid >> 3;
    const int qt  = idx & 7;
    const int bh  = (bid & 7) + 8 * (idx >> 3);
    const int h   = bh % NH;
    const int b   = bh / NH;
    const size_t hbase = ((size_t)b * NH + h) * TT * HD;

    short8 pK[2], pV[2];
    auto loadKV = [&](int kt) {
        #pragma unroll
        for (int ii = 0; ii < 2; ++ii) {
            int u = tid + ii * 256;
            int row = u >> 3, c8 = u & 7;
            pK[ii] = *(const short8*)(K  + hbase + (size_t)(kt*64 + row) * HD + c8*8);
            pV[ii] = *(const short8*)(Vt + hbase + (size_t)row * TT + kt*64 + c8*8);
        }
    };
    auto writeKV = [&](int bf) {
        #pragma unroll
        for (int ii = 0; ii < 2; ++ii) {
            int u = tid + ii * 256;
            int row = u >> 3, c8 = u & 7;
            *(short8*)&sKV[KOFFB(bf) + row*72 + c8*8] = pK[ii];
            *(short8*)&sKV[VOFFB(bf) + row*72 + c8*8] = pV[ii];
        }
    };

    #pragma unroll
    for (int ii = 0; ii < 4; ++ii) {
        int u = tid + ii * 256;
        int row = u >> 3, c8 = u & 7;
        *(short8*)&sKV[row*72 + c8*8] =
            *(const short8*)(Q + hbase + (size_t)(qt*128 + row) * HD + c8*8);
    }
    #pragma unroll
    for (int ii = 0; ii < 2; ++ii) {
        int u = tid + ii * 256;
        if (u < 280) {                 // 35 rows x 8 chunks of relh window
            int row = u >> 3, c8 = u & 7;
            const float* src = relh + (size_t)(4*qt + row) * HD + c8*8;
            float4 v0 = *(const float4*)(src);
            float4 v1 = *(const float4*)(src + 4);
            hv8 s = { (_Float16)(v0.x*LOG2E), (_Float16)(v0.y*LOG2E),
                      (_Float16)(v0.z*LOG2E), (_Float16)(v0.w*LOG2E),
                      (_Float16)(v1.x*LOG2E), (_Float16)(v1.y*LOG2E),
                      (_Float16)(v1.z*LOG2E), (_Float16)(v1.w*LOG2E) };
            *(hv8*)&sKV[9216 + row*72 + c8*8] = s;
        }
    }
    #pragma unroll
    for (int ii = 0; ii < 2; ++ii) {
        int u = tid + ii * 256;
        int row = u >> 3, c8 = u & 7;
        int sr = row < 63 ? row : 62;
        const float* src = relw + (size_t)sr * HD + c8*8;
        float4 v0 = *(const float4*)(src);
        float4 v1 = *(const float4*)(src + 4);
        hv8 s = { (_Float16)(v0.x*LOG2E), (_Float16)(v0.y*LOG2E),
                  (_Float16)(v0.z*LOG2E), (_Float16)(v0.w*LOG2E),
                  (_Float16)(v1.x*LOG2E), (_Float16)(v1.y*LOG2E),
                  (_Float16)(v1.z*LOG2E), (_Float16)(v1.w*LOG2E) };
        *(hv8*)&sKV[13824 + row*72 + c8*8] = s;
    }
    loadKV(0);
    __syncthreads();

    hv8 aQ0[2], aQ1[2];
    #pragma unroll
    for (int g = 0; g < 2; ++g) {
        int qrow = wave*32 + g*16 + l16;
        aQ0[g] = *(const hv8*)&sKV[qrow*72 + quad*8];
        aQ1[g] = *(const hv8*)&sKV[qrow*72 + 32 + quad*8];
    }
    __syncthreads();

    #pragma unroll
    for (int g = 0; g < 2; ++g)
        #pragma unroll
        for (int t = 0; t < 2; ++t) {
            int wr = wave + 31 - (t*16 + l16);
            hv8 b0 = *(const hv8*)&sKV[9216 + wr*72 + quad*8];
            hv8 b1 = *(const hv8*)&sKV[9216 + wr*72 + 32 + quad*8];
            f32x4 c = {0.f,0.f,0.f,0.f};
            c = __builtin_amdgcn_mfma_f32_16x16x32_f16(aQ0[g], b0, c, 0, 0, 0);
            c = __builtin_amdgcn_mfma_f32_16x16x32_f16(aQ1[g], b1, c, 0, 0, 0);
            #pragma unroll
            for (int r = 0; r < 4; ++r)
                sH[wave*32 + g*16 + quad*4 + r][t*16 + l16] = (_Float16)c[r];
        }
    #pragma unroll
    for (int g = 0; g < 2; ++g)
        #pragma unroll
        for (int t = 0; t < 4; ++t) {
            hv8 b0 = *(const hv8*)&sKV[13824 + (t*16 + l16)*72 + quad*8];
            hv8 b1 = *(const hv8*)&sKV[13824 + (t*16 + l16)*72 + 32 + quad*8];
            f32x4 c = {0.f,0.f,0.f,0.f};
            c = __builtin_amdgcn_mfma_f32_16x16x32_f16(aQ0[g], b0, c, 0, 0, 0);
            c = __builtin_amdgcn_mfma_f32_16x16x32_f16(aQ1[g], b1, c, 0, 0, 0);
            #pragma unroll
            for (int r = 0; r < 4; ++r)
                sKV[wave*2304 + (g*16 + quad*4 + r)*72 + t*16 + l16] = (_Float16)c[r];
        }
    float rwSw[2][2][4];
    #pragma unroll
    for (int g = 0; g < 2; ++g)
        #pragma unroll
        for (int j = 0; j < 2; ++j)
            #pragma unroll
            for (int r = 0; r < 4; ++r) {
                int q32 = g*16 + l16;
                int w   = q32 - j*16 - quad*4 - r + 31;   // 0..62
                rwSw[g][j][r] = (float)sKV[wave*2304 + q32*72 + w];
            }
    __syncthreads();
    writeKV(0);
    loadKV(1);
    __syncthreads();

    f32x4 o[2][4];
    #pragma unroll
    for (int g = 0; g < 2; ++g)
        #pragma unroll
        for (int n = 0; n < 4; ++n) o[g][n] = (f32x4){0.f,0.f,0.f,0.f};
    f32x4 lacc[2] = { (f32x4){0.f,0.f,0.f,0.f}, (f32x4){0.f,0.f,0.f,0.f} };
    const hv8 vone = { (_Float16)1.f, (_Float16)1.f, (_Float16)1.f, (_Float16)1.f,
                       (_Float16)1.f, (_Float16)1.f, (_Float16)1.f, (_Float16)1.f };

    for (int kt = 0; kt < 16; ++kt) {
        const int buf = kt & 1;
        if (kt < 15) writeKV(buf ^ 1);
        if (kt < 14) loadKV(kt + 2);

        float rhq[2][2];
        #pragma unroll
        for (int g = 0; g < 2; ++g) {
            unsigned pr = *(const unsigned*)&sH[wave*32 + g*16 + l16][kt*2];
            rhq[g][0] = (float)(*(const _Float16*)&pr);
            rhq[g][1] = (float)(*((const _Float16*)&pr + 1));
        }

        unsigned wpk[2][4][2];
        #pragma unroll
        for (int bb = 0; bb < 4; ++bb) {
            hv8 bK0 = *(const hv8*)&sKV[KOFFB(buf) + (bb*16 + l16)*72 + quad*8];
            hv8 bK1 = *(const hv8*)&sKV[KOFFB(buf) + (bb*16 + l16)*72 + 32 + quad*8];
            #pragma unroll
            for (int g = 0; g < 2; ++g) {
                f32x4 c;
                #pragma unroll
                for (int r = 0; r < 4; ++r)
                    c[r] = rhq[g][bb>>1] + rwSw[g][bb&1][r];
                c = __builtin_amdgcn_mfma_f32_16x16x32_f16(bK0, aQ0[g], c, 0, 0, 0);
                c = __builtin_amdgcn_mfma_f32_16x16x32_f16(bK1, aQ1[g], c, 0, 0, 0);
                #pragma unroll
                for (int rr = 0; rr < 2; ++rr) {
                    union { _Float16 hh[2]; unsigned u; } pu;
                    pu.hh[0] = (_Float16)fast_exp2(c[2*rr]);
                    pu.hh[1] = (_Float16)fast_exp2(c[2*rr+1]);
                    wpk[g][bb][rr] = pu.u;
                }
            }
        }

        hv8 aP[2][2];
        #pragma unroll
        for (int g = 0; g < 2; ++g)
            #pragma unroll
            for (int kk = 0; kk < 2; ++kk) {
                union { unsigned u4[4]; hv8 v; } cv;
                #pragma unroll
                for (int rr = 0; rr < 2; ++rr) {
                    unsigned e = wpk[g][2*kk][rr];
                    unsigned oo = wpk[g][2*kk+1][rr];
                    asm("v_permlane32_swap_b32 %0, %1" : "+v"(e), "+v"(oo));
                    asm("v_permlane16_swap_b32 %0, %1" : "+v"(e), "+v"(oo));
                    cv.u4[rr]     = e;
                    cv.u4[2 + rr] = oo;
                }
                aP[g][kk] = cv.v;
            }

        __builtin_amdgcn_s_setprio(1);
        #pragma unroll
        for (int g = 0; g < 2; ++g) {
            lacc[g] = __builtin_amdgcn_mfma_f32_16x16x32_f16(aP[g][0], vone, lacc[g], 0, 0, 0);
            lacc[g] = __builtin_amdgcn_mfma_f32_16x16x32_f16(aP[g][1], vone, lacc[g], 0, 0, 0);
        }
        #pragma unroll
        for (int nn = 0; nn < 4; ++nn) {
            hv8 bV0 = *(const hv8*)&sKV[VOFFB(buf) + (nn*16 + l16)*72 + quad*8];
            hv8 bV1 = *(const hv8*)&sKV[VOFFB(buf) + (nn*16 + l16)*72 + 32 + quad*8];
            #pragma unroll
            for (int g = 0; g < 2; ++g) {
                o[g][nn] = __builtin_amdgcn_mfma_f32_16x16x32_f16(aP[g][0], bV0, o[g][nn], 0, 0, 0);
                o[g][nn] = __builtin_amdgcn_mfma_f32_16x16x32_f16(aP[g][1], bV1, o[g][nn], 0, 0, 0);
            }
        }
        __builtin_amdgcn_s_setprio(0);

        __syncthreads();
    }

    #pragma unroll
    for (int g = 0; g < 2; ++g) {
        float inv[4];
        #pragma unroll
        for (int r = 0; r < 4; ++r) inv[r] = 1.f / lacc[g][r];
        #pragma unroll
        for (int n = 0; n < 4; ++n)
            #pragma unroll
            for (int r = 0; r < 4; ++r) {
                int t = qt*128 + wave*32 + g*16 + quad*4 + r;
                size_t addr = ((size_t)b * TT + t) * CC + h*HD + n*16 + l16;
                O[addr] = (_Float16)(o[g][n][r] * inv[r]);
            }
    }
}

// ---------------------------------------------------------------------------
extern "C" void kernel_launch(void* const* d_in, const int* in_sizes, int n_in,
                              void* d_out, int out_size, void* d_ws, size_t ws_size,
                              hipStream_t stream) {
    const float* x   = (const float*)d_in[0];
    const float* ctx = (const float*)d_in[1];
    const float* Wq  = (const float*)d_in[2];
    const float* Wk  = (const float*)d_in[3];
    const float* Wv  = (const float*)d_in[4];
    const float* Wo  = (const float*)d_in[5];
    const float* bo  = (const float*)d_in[6];
    const float* rh  = (const float*)d_in[7];
    const float* rw  = (const float*)d_in[8];
    float* out = (float*)d_out;

    const size_t MN = (size_t)BB * TT * CC;   // 6291456
    const size_t WN = (size_t)CC * CC;        // 589824
    _Float16* p = (_Float16*)d_ws;
    _Float16* xh  = p; p += MN;
    _Float16* ch  = p; p += MN;
    _Float16* WqT = p; p += WN;
    _Float16* WkT = p; p += WN;
    _Float16* WvT = p; p += WN;
    _Float16* WoT = p; p += WN;
    _Float16* Qh  = p; p += MN;
    _Float16* Kh  = p; p += MN;
    _Float16* VtB = p; p += MN;
    _Float16* Oh  = p; p += MN;

    dim3 blk(256);

    prep_fused<<<dim3(6720), blk, 0, stream>>>(
        x, ctx, xh, ch, (int)MN, Wq, Wk, Wv, Wo, WqT, WkT, WvT, WoT);

    gemm_qkv3<<<dim3(1152), blk, 0, stream>>>(
        xh, ch, WqT, WkT, WvT, Qh, Kh, VtB);

    attn_mfma<<<dim3(BB*NH*(TT/128)), blk, 0, stream>>>(
        Qh, Kh, VtB, rh, rw, Oh);

    gemm_out_f16<<<dim3(768), blk, 0, stream>>>(
        Oh, WoT, bo, out);
}